// Round 5
// baseline (2756.880 us; speedup 1.0000x reference)
//
#include <hip/hip_runtime.h>
#include <hip/hip_bf16.h>
#include <stdint.h>

#define NN      50000
#define MMN     12
#define NMROWS  600000
#define ORIGF   92
#define NBRF    41
#define AFD     64
#define GCH     128
#define KTOT    169
#define BBC     500
#define NAA     100
#define BN_EPS  1e-5f
#define GROWS   96

typedef unsigned short u16;
typedef __attribute__((ext_vector_type(8))) short bf16x8;
typedef __attribute__((ext_vector_type(4))) float f32x4;

__device__ __forceinline__ float b2f(u16 u) {
    union { uint32_t i; float f; } v; v.i = ((uint32_t)u) << 16; return v.f;
}
__device__ __forceinline__ float hi2f(uint32_t p) {
    union { uint32_t i; float f; } v; v.i = p & 0xffff0000u; return v.f;
}
__device__ __forceinline__ u16 f2b(float f) {
    __hip_bfloat16 h = __float2bfloat16(f);
    return *(u16*)&h;
}
// branchless fast softplus: max(x,0) + log(1 + exp(-|x|))
__device__ __forceinline__ float sp_f(float x) {
    return fmaxf(x, 0.f) + __logf(1.f + __expf(-fabsf(x)));
}
__device__ __forceinline__ float sigm_f(float x) {
    return __builtin_amdgcn_rcpf(1.f + __expf(-x));
}
// async global->LDS: 64 lanes x 4B, LDS dest = uniform base + lane*4
__device__ __forceinline__ void gll4(const void* g, void* l) {
    __builtin_amdgcn_global_load_lds(
        (const __attribute__((address_space(1))) void*)g,
        (__attribute__((address_space(3))) void*)l, 4, 0, 0);
}

// ---------------- output 1: atom_fea * mask (fp32) ----------------
__global__ void k_mask(const float* __restrict__ atom, const float* __restrict__ mask,
                       float* __restrict__ dout) {
    int i = blockIdx.x * blockDim.x + threadIdx.x;
    int stride = gridDim.x * blockDim.x;
    for (; i < NN * ORIGF; i += stride) {
        int k = i % ORIGF;
        dout[BBC + i] = atom[i] * mask[k];
    }
}

// ---------------- h = (atom*mask) @ emb_W^T  (bf16 out) ----------------
__global__ __launch_bounds__(256, 2) void k_emb(const float* __restrict__ atom,
                                                const float* __restrict__ mask,
                                                const float* __restrict__ embW,
                                                u16* __restrict__ h) {
    __shared__ float xs[4 * 96];
    int lane = threadIdx.x & 63;
    int w = threadIdx.x >> 6;
    float wr[ORIGF];
#pragma unroll
    for (int k = 0; k < ORIGF; ++k) wr[k] = embW[lane * ORIGF + k];
    float m1 = mask[lane];
    float m2 = (lane < ORIGF - 64) ? mask[64 + lane] : 0.f;
    for (int base = blockIdx.x * 4; base < NN; base += gridDim.x * 4) {
        int n = base + w;   // NN % 4 == 0
        xs[w * 96 + lane] = atom[(size_t)n * ORIGF + lane] * m1;
        if (lane < ORIGF - 64)
            xs[w * 96 + 64 + lane] = atom[(size_t)n * ORIGF + 64 + lane] * m2;
        __syncthreads();
        float acc = 0.f;
#pragma unroll
        for (int k4 = 0; k4 < ORIGF / 4; ++k4) {
            float4 f = *(const float4*)&xs[w * 96 + 4 * k4];
            acc += f.x * wr[4*k4] + f.y * wr[4*k4+1] + f.z * wr[4*k4+2] + f.w * wr[4*k4+3];
        }
        h[(size_t)n * AFD + lane] = f2b(acc);
        __syncthreads();
    }
}

// ------- C (bf16 pairs): (h@Wc^T | h@Wn^T) -------
// u32 word layout: C32[n*128 + lane]      = (C1[ch=lane], C1[ch=lane+64])
//                  C32[n*128 + 64 + lane] = (C2[ch=lane], C2[ch=lane+64])
__global__ __launch_bounds__(256, 2) void k_cn(const u16* __restrict__ h,
                                               const float* __restrict__ convW,
                                               uint32_t* __restrict__ C32) {
    __shared__ float xs[2 * AFD];
    int lane = threadIdx.x & 63;
    int w = threadIdx.x >> 6;
    int half = w & 1;
    int sub = w >> 1;
    int koff = half * AFD;
    float wa[AFD], wb[AFD];
#pragma unroll
    for (int k = 0; k < AFD; ++k) {
        wa[k] = convW[lane * KTOT + koff + k];
        wb[k] = convW[(lane + 64) * KTOT + koff + k];
    }
    for (int base = blockIdx.x * 2; base < NN; base += gridDim.x * 2) {
        int n = base + sub;   // NN % 2 == 0
        if (half == 0) xs[sub * AFD + lane] = b2f(h[(size_t)n * AFD + lane]);
        __syncthreads();
        float aa = 0.f, ab = 0.f;
#pragma unroll
        for (int k4 = 0; k4 < AFD / 4; ++k4) {
            float4 f = *(const float4*)&xs[sub * AFD + 4 * k4];
            aa += f.x * wa[4*k4] + f.y * wa[4*k4+1] + f.z * wa[4*k4+2] + f.w * wa[4*k4+3];
            ab += f.x * wb[4*k4] + f.y * wb[4*k4+1] + f.z * wb[4*k4+2] + f.w * wb[4*k4+3];
        }
        C32[(size_t)n * 128 + half * 64 + lane] = (uint32_t)f2b(aa) | ((uint32_t)f2b(ab) << 16);
        __syncthreads();
    }
}

// ------- conv pass (MFMA, async-gather, NO gated materialization) -------
// PASS 1: gated = nbrf@Wf^T (+bias col) + C1 + C2 via MFMA; accumulate BN1
//         sum/sumsq only (no global store of gated).
// PASS 2: recompute gated identically (deterministic), apply BN1 + act,
//         reduce 12 edges/atom in-block (LDS f32 atomics), write summed
//         (6.4 MB) + BN2 sums. Replaces the 310 MB/layer gated round-trip.
// Gathers (C1 center rows, C2 neighbor rows) use global_load_lds: zero VGPR,
// all 26/wave in flight; nbridx via readfirstlane-forced scalar loads.
// D layout (HW-verified): col = lane&15, row = (lane>>4)*4 + reg.
template<int PASS>
__global__ __launch_bounds__(256, 4) void k_gs6(
    const uint32_t* __restrict__ C32, const float* __restrict__ nbrf,
    const int* __restrict__ nbridx, const float* __restrict__ convW,
    const float* __restrict__ convb, float* __restrict__ stats,
    u16* __restrict__ summed)
{
    __shared__ __align__(16) u16 As[GROWS * 48];   // 9216 B, k=0..47 (41=bias)
    __shared__ uint32_t C2s[GROWS * 64];           // 24576 B, linear (gll dest)
    __shared__ uint32_t C1s[8 * 64];               // 2048 B, linear (gll dest)
    __shared__ float sred[8 * 64];                 // 2048 B (PASS 2 atom-reduce)
    const int tid  = threadIdx.x;
    const int lane = tid & 63;
    const int w    = tid >> 6;
    const int lr   = lane & 15;
    const int lg   = lane >> 4;
    const int r0    = blockIdx.x * GROWS;
    const int nbase = blockIdx.x * 8;              // 8 atoms per block
    const int wq   = __builtin_amdgcn_readfirstlane(w);
    const int rowb = wq * 24;                      // rows staged by this wave

    // ---- C1: 2 atoms/wave, async direct-to-LDS ----
    {
        int a0 = wq * 2;
        gll4(&C32[(size_t)(nbase + a0) * 128 + lane],     &C1s[a0 * 64]);
        gll4(&C32[(size_t)(nbase + a0 + 1) * 128 + lane], &C1s[(a0 + 1) * 64]);
    }
    // ---- C2: 24 rows/wave, async direct-to-LDS; nbridx via s_load ----
    const int* nb = nbridx + r0 + rowb;
#pragma unroll
    for (int rr = 0; rr < 24; ++rr) {
        int j = nb[rr];    // uniform address -> scalar load
        gll4(&C32[(size_t)j * 128 + 64 + lane], &C2s[(rowb + rr) * 64]);
    }
    // ---- As loads (96x41 fp32, coalesced float4) ----
    const float4* src4 = (const float4*)(nbrf + (size_t)r0 * NBRF);  // 16B aligned
    float4 af[4];
#pragma unroll
    for (int it = 0; it < 4; ++it) {
        int t = tid + it * 256;
        if (it < 3 || t < 984) af[it] = src4[t];     // 984 = 96*41/4
    }
    // ---- B frags direct from global (L2-hot), same k-mapping as A ----
    const int chlo = w * 16 + lr;
    const int chhi = chlo + 64;
    const float* wlo = convW + (size_t)chlo * KTOT + 128;
    const float* whi = convW + (size_t)chhi * KTOT + 128;
    bf16x8 bl0, bh0;
    bf16x8 bl1 = {0,0,0,0,0,0,0,0}, bh1 = {0,0,0,0,0,0,0,0};
#pragma unroll
    for (int e = 0; e < 8; ++e) {
        bl0[e] = (short)f2b(wlo[8 * lg + e]);
        bh0[e] = (short)f2b(whi[8 * lg + e]);
    }
    if (lg == 0) {
#pragma unroll
        for (int e = 0; e < 8; ++e) {
            bl1[e] = (short)f2b(wlo[32 + e]);
            bh1[e] = (short)f2b(whi[32 + e]);
        }
    } else if (lg == 1) {
        bl1[0] = (short)f2b(wlo[40]); bl1[1] = (short)f2b(convb[chlo]);
        bh1[0] = (short)f2b(whi[40]); bh1[1] = (short)f2b(convb[chhi]);
    }
    // ---- BN1 scale/shift (PASS 2 only; stats L2-hot) ----
    const int word = w * 16 + lr;   // u32 word = (ch, ch+64)
    float sa = 0.f, ba = 0.f, sb = 0.f, bbv = 0.f;
    if (PASS == 2) {
        sa = stats[384 + word];      ba = stats[512 + word];
        sb = stats[384 + 64 + word]; bbv = stats[512 + 64 + word];
    }
    // ---- As convert + LDS write (hides gather latency) ----
#pragma unroll
    for (int it = 0; it < 4; ++it) {
        int t = tid + it * 256;
        if (it < 3 || t < 984) {
            float4 f = af[it];
            float vals[4] = {f.x, f.y, f.z, f.w};
#pragma unroll
            for (int jj = 0; jj < 4; ++jj) {
                int e = t * 4 + jj;
                int row = e / NBRF;
                int k = e - row * NBRF;
                As[row * 48 + k] = f2b(vals[jj]);
            }
        }
    }
    // As pad: k=41 -> 1.0 (bias column), 42..47 -> 0   (96*7 = 672 elems)
    for (int e = tid; e < 672; e += 256) {
        int row = e / 7;
        int k = 41 + (e - row * 7);
        As[row * 48 + k] = (k == 41) ? (u16)0x3F80 : (u16)0;
    }
    if (PASS == 2) {
        sred[tid] = 0.f; sred[tid + 256] = 0.f;
    }
    __syncthreads();   // drains vmcnt (all gll) + lgkm

    // ---- MFMA: 6 M-tiles x 2 channel halves ----
    f32x4 acc[6][2];
    const f32x4 z = {0.f, 0.f, 0.f, 0.f};
    const bf16x8 zb = {0,0,0,0,0,0,0,0};
#pragma unroll
    for (int mt = 0; mt < 6; ++mt) {
        const u16* ap = &As[(mt * 16 + lr) * 48 + 8 * lg];
        bf16x8 a0 = *(const bf16x8*)ap;
        bf16x8 a1 = zb;
        if (lg < 2) a1 = *(const bf16x8*)(ap + 32);   // k = 32+8lg..39+8lg (<48)
        acc[mt][0] = __builtin_amdgcn_mfma_f32_16x16x32_bf16(a1, bl1,
                     __builtin_amdgcn_mfma_f32_16x16x32_bf16(a0, bl0, z, 0, 0, 0), 0, 0, 0);
        acc[mt][1] = __builtin_amdgcn_mfma_f32_16x16x32_bf16(a1, bh1,
                     __builtin_amdgcn_mfma_f32_16x16x32_bf16(a0, bh0, z, 0, 0, 0), 0, 0, 0);
    }

    if (PASS == 1) {
        // ---- BN1 sum/sumsq over all 128 channels ----
        float slo = 0.f, qlo = 0.f, shi = 0.f, qhi = 0.f;
#pragma unroll
        for (int mt = 0; mt < 6; ++mt) {
            int atom = (mt * 16 + 4 * lg) / 12;   // rows of this (mt,lg) share atom
            uint32_t p1 = C1s[atom * 64 + word];
            float c1lo = b2f((u16)p1), c1hi = hi2f(p1);
#pragma unroll
            for (int rg = 0; rg < 4; ++rg) {
                int row = mt * 16 + 4 * lg + rg;
                uint32_t p2 = C2s[row * 64 + word];
                float glo = acc[mt][0][rg] + c1lo + b2f((u16)p2);
                float ghi = acc[mt][1][rg] + c1hi + hi2f(p2);
                slo += glo; qlo = fmaf(glo, glo, qlo);
                shi += ghi; qhi = fmaf(ghi, ghi, qhi);
            }
        }
        // lanes {lr, lr+16, lr+32, lr+48} hold the same channel -> butterfly
        slo += __shfl_xor(slo, 16, 64); slo += __shfl_xor(slo, 32, 64);
        qlo += __shfl_xor(qlo, 16, 64); qlo += __shfl_xor(qlo, 32, 64);
        shi += __shfl_xor(shi, 16, 64); shi += __shfl_xor(shi, 32, 64);
        qhi += __shfl_xor(qhi, 16, 64); qhi += __shfl_xor(qhi, 32, 64);
        if (lane < 16) {
            atomicAdd(&stats[word], slo);
            atomicAdd(&stats[128 + word], qlo);
            atomicAdd(&stats[64 + word], shi);
            atomicAdd(&stats[128 + 64 + word], qhi);
        }
    } else {
        // ---- recompute + BN1 + act, reduce edges->atom in LDS ----
#pragma unroll
        for (int mt = 0; mt < 6; ++mt) {
            int atom = (mt * 16 + 4 * lg) / 12;
            uint32_t p1 = C1s[atom * 64 + word];
            float c1lo = b2f((u16)p1), c1hi = hi2f(p1);
            float pm = 0.f;
#pragma unroll
            for (int rg = 0; rg < 4; ++rg) {
                int row = mt * 16 + 4 * lg + rg;
                uint32_t p2 = C2s[row * 64 + word];
                float glo = acc[mt][0][rg] + c1lo + b2f((u16)p2);
                float ghi = acc[mt][1][rg] + c1hi + hi2f(p2);
                pm += sigm_f(glo * sa + ba) * sp_f(ghi * sb + bbv);
            }
            atomicAdd(&sred[atom * 64 + word], pm);
        }
        __syncthreads();
        // ---- write summed (u16) + BN2 sum/sumsq ----
        int word2 = tid & 63;
        int a = tid >> 6;
        float v1 = sred[a * 64 + word2];
        float v2 = sred[(a + 4) * 64 + word2];
        summed[(size_t)(nbase + a) * AFD + word2] = f2b(v1);
        summed[(size_t)(nbase + a + 4) * AFD + word2] = f2b(v2);
        atomicAdd(&stats[256 + word2], v1 + v2);
        atomicAdd(&stats[320 + word2], v1 * v1 + v2 * v2);
    }
}

// ------- finalize BN: scale/shift from sums -------
__global__ void k_fin(float* __restrict__ stats, const float* __restrict__ gg,
                      const float* __restrict__ bb, int nch, float invcnt,
                      int sumoff, int sqoff, int scoff, int shoff) {
    int c = threadIdx.x;
    if (c < nch) {
        float mean = stats[sumoff + c] * invcnt;
        float var  = fmaxf(stats[sqoff + c] * invcnt - mean * mean, 0.f);
        float sc   = gg[c] * rsqrtf(var + BN_EPS);
        stats[scoff + c] = sc;
        stats[shoff + c] = bb[c] - mean * sc;
    }
}

// ------- h = softplus(h + BN2(summed))  (bf16 h) -------
__global__ void k_update(u16* __restrict__ h, const u16* __restrict__ summed,
                         const float* __restrict__ stats) {
    int i = blockIdx.x * blockDim.x + threadIdx.x;
    int st = gridDim.x * blockDim.x;
    int c = threadIdx.x & 63;
    float sc = stats[640 + c], shf = stats[704 + c];
    for (; i < NN * AFD; i += st) {
        float x = b2f(h[i]) + b2f(summed[i]) * sc + shf;
        h[i] = f2b(sp_f(x));
    }
}

// ------- row-normalize + mean-pool per crystal -------
__global__ __launch_bounds__(256) void k_pool(const u16* __restrict__ h,
                                              const int* __restrict__ cry,
                                              float* __restrict__ pooled) {
    __shared__ float red[4][64];
    int lane = threadIdx.x & 63, w = threadIdx.x >> 6;
    int b = blockIdx.x;
    float acc = 0.f;
    for (int a = w; a < NAA; a += 4) {
        int idx = cry[b * NAA + a];
        float v = b2f(h[(size_t)idx * AFD + lane]);
        float s2 = v * v;
#pragma unroll
        for (int o = 32; o > 0; o >>= 1) s2 += __shfl_xor(s2, o, 64);
        acc += v / fmaxf(sqrtf(s2), 1e-12f);
    }
    red[w][lane] = acc;
    __syncthreads();
    if (threadIdx.x < 64) {
        float s = red[0][threadIdx.x] + red[1][threadIdx.x] +
                  red[2][threadIdx.x] + red[3][threadIdx.x];
        pooled[b * AFD + threadIdx.x] = s * (1.f / NAA);
    }
}

// ------- MLP head (fp32 out) -------
__global__ __launch_bounds__(64) void k_head(const float* __restrict__ pooled,
    const float* __restrict__ fc1W, const float* __restrict__ fc1b,
    const float* __restrict__ fc2W, const float* __restrict__ fc2b,
    const float* __restrict__ outW, const float* __restrict__ outb,
    float* __restrict__ props) {
    __shared__ float W1[64 * 65], W2[64 * 65], zbuf[64], pbuf[64];
    int l = threadIdx.x;
    for (int e = l; e < 64 * 64; e += 64) {
        int o = e >> 6, k = e & 63;
        W1[o * 65 + k] = fc1W[e];
        W2[o * 65 + k] = fc2W[e];
    }
    int b = blockIdx.x;
    pbuf[l] = pooled[b * AFD + l];
    __syncthreads();
    float acc = fc1b[l];
#pragma unroll
    for (int k = 0; k < 64; ++k) acc += pbuf[k] * W1[l * 65 + k];
    zbuf[l] = sp_f(acc);
    __syncthreads();
    acc = fc2b[l];
#pragma unroll
    for (int k = 0; k < 64; ++k) acc += zbuf[k] * W2[l * 65 + k];
    float v = sp_f(acc) * outW[l];
#pragma unroll
    for (int o = 32; o > 0; o >>= 1) v += __shfl_xor(v, o, 64);
    if (l == 0) props[b] = v + outb[0];
}

extern "C" void kernel_launch(void* const* d_in, const int* in_sizes, int n_in,
                              void* d_out, int out_size, void* d_ws, size_t ws_size,
                              hipStream_t stream) {
    const float* atom  = (const float*)d_in[0];
    const float* nbrf  = (const float*)d_in[1];
    const int* nbridx  = (const int*)d_in[2];
    const int* cry     = (const int*)d_in[3];
    const float* mask  = (const float*)d_in[4];
    const float* embW  = (const float*)d_in[5];
    const float* convW = (const float*)d_in[6];
    const float* convb = (const float*)d_in[7];
    const float* bn1g  = (const float*)d_in[8];
    const float* bn1b  = (const float*)d_in[9];
    const float* bn2g  = (const float*)d_in[10];
    const float* bn2b  = (const float*)d_in[11];
    const float* fc1W  = (const float*)d_in[12];
    const float* fc1b  = (const float*)d_in[13];
    const float* fc2W  = (const float*)d_in[14];
    const float* fc2b  = (const float*)d_in[15];
    const float* outW  = (const float*)d_in[16];
    const float* outb  = (const float*)d_in[17];

    char* ws = (char*)d_ws;
    float* stats    = (float*)ws;                      // 768 floats
    float* pooled   = (float*)(ws + 4096);             // 128,000 B
    u16*   h        = (u16*)(ws + (1u << 20));         // 6.4 MB
    u16*   summed   = (u16*)(ws + (8u << 20));         // 6.4 MB
    uint32_t* C32   = (uint32_t*)(ws + (16u << 20));   // 25.6 MB

    float* out_props = (float*)d_out;

    k_mask<<<2048, 256, 0, stream>>>(atom, mask, (float*)d_out);
    k_emb<<<512, 256, 0, stream>>>(atom, mask, embW, h);
    for (int i = 0; i < 3; ++i) {
        hipMemsetAsync(stats, 0, 384 * sizeof(float), stream);
        k_cn<<<1024, 256, 0, stream>>>(h, convW + (size_t)i * GCH * KTOT, C32);
        k_gs6<1><<<NMROWS / GROWS, 256, 0, stream>>>(C32, nbrf, nbridx,
            convW + (size_t)i * GCH * KTOT, convb + (size_t)i * GCH, stats, summed);
        k_fin<<<1, 128, 0, stream>>>(stats, bn1g + (size_t)i * GCH, bn1b + (size_t)i * GCH,
                                     128, 1.f / NMROWS, 0, 128, 384, 512);
        k_gs6<2><<<NMROWS / GROWS, 256, 0, stream>>>(C32, nbrf, nbridx,
            convW + (size_t)i * GCH * KTOT, convb + (size_t)i * GCH, stats, summed);
        k_fin<<<1, 128, 0, stream>>>(stats, bn2g + (size_t)i * AFD, bn2b + (size_t)i * AFD,
                                     64, 1.f / NN, 256, 320, 640, 704);
        k_update<<<1024, 256, 0, stream>>>(h, summed, stats);
    }
    k_pool<<<BBC, 256, 0, stream>>>(h, cry, pooled);
    k_head<<<BBC, 64, 0, stream>>>(pooled, fc1W, fc1b, fc2W, fc2b, outW, outb, out_props);
}

// Round 6
// 1539.776 us; speedup vs baseline: 1.7904x; 1.7904x over previous
//
#include <hip/hip_runtime.h>
#include <hip/hip_bf16.h>
#include <stdint.h>

#define NN      50000
#define MMN     12
#define NMROWS  600000
#define ORIGF   92
#define NBRF    41
#define AFD     64
#define GCH     128
#define KTOT    169
#define BBC     500
#define NAA     100
#define BN_EPS  1e-5f
#define GROWS   96
#define G48     48

typedef unsigned short u16;
typedef __attribute__((ext_vector_type(8))) short bf16x8;
typedef __attribute__((ext_vector_type(4))) float f32x4;

__device__ __forceinline__ float b2f(u16 u) {
    union { uint32_t i; float f; } v; v.i = ((uint32_t)u) << 16; return v.f;
}
__device__ __forceinline__ float hi2f(uint32_t p) {
    union { uint32_t i; float f; } v; v.i = p & 0xffff0000u; return v.f;
}
__device__ __forceinline__ u16 f2b(float f) {
    __hip_bfloat16 h = __float2bfloat16(f);
    return *(u16*)&h;
}
// branchless fast softplus: max(x,0) + log(1 + exp(-|x|))
__device__ __forceinline__ float sp_f(float x) {
    return fmaxf(x, 0.f) + __logf(1.f + __expf(-fabsf(x)));
}
__device__ __forceinline__ float sigm_f(float x) {
    return __builtin_amdgcn_rcpf(1.f + __expf(-x));
}

// ---------------- output 1: atom_fea * mask (fp32) ----------------
__global__ void k_mask(const float* __restrict__ atom, const float* __restrict__ mask,
                       float* __restrict__ dout) {
    int i = blockIdx.x * blockDim.x + threadIdx.x;
    int stride = gridDim.x * blockDim.x;
    for (; i < NN * ORIGF; i += stride) {
        int k = i % ORIGF;
        dout[BBC + i] = atom[i] * mask[k];
    }
}

// ---------------- h = (atom*mask) @ emb_W^T  (bf16 out) ----------------
__global__ __launch_bounds__(256, 2) void k_emb(const float* __restrict__ atom,
                                                const float* __restrict__ mask,
                                                const float* __restrict__ embW,
                                                u16* __restrict__ h) {
    __shared__ float xs[4 * 96];
    int lane = threadIdx.x & 63;
    int w = threadIdx.x >> 6;
    float wr[ORIGF];
#pragma unroll
    for (int k = 0; k < ORIGF; ++k) wr[k] = embW[lane * ORIGF + k];
    float m1 = mask[lane];
    float m2 = (lane < ORIGF - 64) ? mask[64 + lane] : 0.f;
    for (int base = blockIdx.x * 4; base < NN; base += gridDim.x * 4) {
        int n = base + w;   // NN % 4 == 0
        xs[w * 96 + lane] = atom[(size_t)n * ORIGF + lane] * m1;
        if (lane < ORIGF - 64)
            xs[w * 96 + 64 + lane] = atom[(size_t)n * ORIGF + 64 + lane] * m2;
        __syncthreads();
        float acc = 0.f;
#pragma unroll
        for (int k4 = 0; k4 < ORIGF / 4; ++k4) {
            float4 f = *(const float4*)&xs[w * 96 + 4 * k4];
            acc += f.x * wr[4*k4] + f.y * wr[4*k4+1] + f.z * wr[4*k4+2] + f.w * wr[4*k4+3];
        }
        h[(size_t)n * AFD + lane] = f2b(acc);
        __syncthreads();
    }
}

// ------- C (bf16 pairs): (h@Wc^T | h@Wn^T) -------
// u32 word layout: C32[n*128 + lane]      = (C1[ch=lane], C1[ch=lane+64])
//                  C32[n*128 + 64 + lane] = (C2[ch=lane], C2[ch=lane+64])
__global__ __launch_bounds__(256, 2) void k_cn(const u16* __restrict__ h,
                                               const float* __restrict__ convW,
                                               uint32_t* __restrict__ C32) {
    __shared__ float xs[2 * AFD];
    int lane = threadIdx.x & 63;
    int w = threadIdx.x >> 6;
    int half = w & 1;
    int sub = w >> 1;
    int koff = half * AFD;
    float wa[AFD], wb[AFD];
#pragma unroll
    for (int k = 0; k < AFD; ++k) {
        wa[k] = convW[lane * KTOT + koff + k];
        wb[k] = convW[(lane + 64) * KTOT + koff + k];
    }
    for (int base = blockIdx.x * 2; base < NN; base += gridDim.x * 2) {
        int n = base + sub;   // NN % 2 == 0
        if (half == 0) xs[sub * AFD + lane] = b2f(h[(size_t)n * AFD + lane]);
        __syncthreads();
        float aa = 0.f, ab = 0.f;
#pragma unroll
        for (int k4 = 0; k4 < AFD / 4; ++k4) {
            float4 f = *(const float4*)&xs[sub * AFD + 4 * k4];
            aa += f.x * wa[4*k4] + f.y * wa[4*k4+1] + f.z * wa[4*k4+2] + f.w * wa[4*k4+3];
            ab += f.x * wb[4*k4] + f.y * wb[4*k4+1] + f.z * wb[4*k4+2] + f.w * wb[4*k4+3];
        }
        C32[(size_t)n * 128 + half * 64 + lane] = (uint32_t)f2b(aa) | ((uint32_t)f2b(ab) << 16);
        __syncthreads();
    }
}

// stage 96 fp32 rows of nbr_fea into fs[row*44 + k]  (Path B fallback only)
__device__ __forceinline__ void stage_nbrf(const float* nbrf, int r0, float* fs) {
    const float4* src = (const float4*)(nbrf + (size_t)r0 * NBRF);
    for (int t = threadIdx.x; t < (GROWS * NBRF) / 4; t += 256) {
        float4 f = src[t];
        float vals[4] = {f.x, f.y, f.z, f.w};
#pragma unroll
        for (int j = 0; j < 4; ++j) {
            int e = t * 4 + j;
            int row = e / NBRF;
            int k = e - row * NBRF;
            fs[row * 44 + k] = vals[j];
        }
    }
}

// ------- pass 1 (MFMA, 8 blocks/CU): gated = nbrf @ Wf^T (+bias) + C1 + C2 -------
// 48 edges x 128 ch per block; LDS 18.75KB + VGPR<=64 (__launch_bounds 256,8)
// => 32 waves/CU for latency hiding (the compiler-proof lever; per-wave load
// batching defeated source-level ILP in rounds 3-5).
// VGPR-staged gathers (global_load_lds regressed 3.4x in round 5 - do not use).
// D layout (HW-verified): col = lane&15, row = (lane>>4)*4 + reg. A/B share the
// identical lane->k mapping so HW K-permutation cancels; k=41 col carries bias.
template<bool STORE>
__global__ __launch_bounds__(256, 8) void k_gs9(
    const uint32_t* __restrict__ C32, const float* __restrict__ nbrf,
    const int* __restrict__ nbridx, const float* __restrict__ convW,
    const float* __restrict__ convb, float* __restrict__ stats,
    uint32_t* __restrict__ gated32)
{
    __shared__ __align__(16) u16 As[G48 * 48];     // 4608 B, k=0..47 (41=bias)
    __shared__ uint32_t C2s[G48 * 68];             // 13056 B, stride 68 (2-way banks)
    __shared__ uint32_t C1s[4 * 68];               // 1088 B
    const int tid  = threadIdx.x;
    const int lane = tid & 63;
    const int w    = tid >> 6;
    const int lr   = lane & 15;
    const int lg   = lane >> 4;
    const int r0    = blockIdx.x * G48;
    const int nbase = blockIdx.x * 4;              // 4 atoms per block
    const int wq   = __builtin_amdgcn_readfirstlane(w);
    const int rowb = wq * 12;                      // rows staged by this wave

    // ---- issue C1 (4 atoms x 64 words, 1 coalesced load/thread) ----
    uint32_t c1v = C32[(size_t)(nbase + (tid >> 6)) * 128 + (tid & 63)];
    // ---- issue C2: 12 rows/wave; nbridx via uniform s_loads ----
    const int* nb = nbridx + r0 + rowb;
    uint32_t c2v[12];
#pragma unroll
    for (int rr = 0; rr < 12; ++rr) {
        int j = nb[rr];
        c2v[rr] = C32[(size_t)j * 128 + 64 + lane];
    }
    // ---- issue As loads (48x41 fp32 = 492 float4, coalesced) ----
    const float4* src4 = (const float4*)(nbrf + (size_t)r0 * NBRF);  // 16B aligned
    float4 af[2];
#pragma unroll
    for (int it = 0; it < 2; ++it) {
        int t = tid + it * 256;
        if (it == 0 || t < 492) af[it] = src4[t];
    }
    // ---- B frags direct from global (L2-hot), same k-mapping as A ----
    const int chlo = w * 16 + lr;
    const int chhi = chlo + 64;
    const float* wlo = convW + (size_t)chlo * KTOT + 128;
    const float* whi = convW + (size_t)chhi * KTOT + 128;
    bf16x8 bl0, bh0;
    bf16x8 bl1 = {0,0,0,0,0,0,0,0}, bh1 = {0,0,0,0,0,0,0,0};
#pragma unroll
    for (int e = 0; e < 8; ++e) {
        bl0[e] = (short)f2b(wlo[8 * lg + e]);
        bh0[e] = (short)f2b(whi[8 * lg + e]);
    }
    if (lg == 0) {
#pragma unroll
        for (int e = 0; e < 8; ++e) {
            bl1[e] = (short)f2b(wlo[32 + e]);
            bh1[e] = (short)f2b(whi[32 + e]);
        }
    } else if (lg == 1) {
        bl1[0] = (short)f2b(wlo[40]); bl1[1] = (short)f2b(convb[chlo]);
        bh1[0] = (short)f2b(whi[40]); bh1[1] = (short)f2b(convb[chhi]);
    }
    // ---- As convert + LDS write (hides gather latency) ----
#pragma unroll
    for (int it = 0; it < 2; ++it) {
        int t = tid + it * 256;
        if (it == 0 || t < 492) {
            float4 f = af[it];
            float vals[4] = {f.x, f.y, f.z, f.w};
#pragma unroll
            for (int jj = 0; jj < 4; ++jj) {
                int e = t * 4 + jj;
                int row = e / NBRF;
                int k = e - row * NBRF;
                As[row * 48 + k] = f2b(vals[jj]);
            }
        }
    }
    // As pad: k=41 -> 1.0 (bias column), 42..47 -> 0   (48*7 = 336 elems)
    for (int e = tid; e < 336; e += 256) {
        int row = e / 7;
        int k = 41 + (e - row * 7);
        As[row * 48 + k] = (k == 41) ? (u16)0x3F80 : (u16)0;
    }
    // ---- C1/C2 LDS writes ----
    C1s[(tid >> 6) * 68 + (tid & 63)] = c1v;
#pragma unroll
    for (int rr = 0; rr < 12; ++rr) C2s[(rowb + rr) * 68 + lane] = c2v[rr];
    __syncthreads();

    // ---- MFMA: 3 M-tiles x 2 channel halves ----
    f32x4 acc[3][2];
    const f32x4 z = {0.f, 0.f, 0.f, 0.f};
    const bf16x8 zb = {0,0,0,0,0,0,0,0};
#pragma unroll
    for (int mt = 0; mt < 3; ++mt) {
        const u16* ap = &As[(mt * 16 + lr) * 48 + 8 * lg];
        bf16x8 a0 = *(const bf16x8*)ap;
        bf16x8 a1 = zb;
        if (lg < 2) a1 = *(const bf16x8*)(ap + 32);   // k = 32+8lg..39+8lg (<48)
        acc[mt][0] = __builtin_amdgcn_mfma_f32_16x16x32_bf16(a1, bl1,
                     __builtin_amdgcn_mfma_f32_16x16x32_bf16(a0, bl0, z, 0, 0, 0), 0, 0, 0);
        acc[mt][1] = __builtin_amdgcn_mfma_f32_16x16x32_bf16(a1, bh1,
                     __builtin_amdgcn_mfma_f32_16x16x32_bf16(a0, bh0, z, 0, 0, 0), 0, 0, 0);
    }

    // ---- epilogue: combine with C1+C2 (LDS), pack-store gated, stats ----
    const int word = w * 16 + lr;   // u32 word = (ch, ch+64)
    float slo = 0.f, qlo = 0.f, shi = 0.f, qhi = 0.f;
#pragma unroll
    for (int mt = 0; mt < 3; ++mt) {
        int atomi = (mt * 16 + 4 * lg) / 12;   // 4-row groups never cross atoms
        uint32_t p1 = C1s[atomi * 68 + word];
        float c1lo = b2f((u16)p1), c1hi = hi2f(p1);
#pragma unroll
        for (int rg = 0; rg < 4; ++rg) {
            int row = mt * 16 + 4 * lg + rg;
            uint32_t p2 = C2s[row * 68 + word];
            float glo = acc[mt][0][rg] + c1lo + b2f((u16)p2);
            float ghi = acc[mt][1][rg] + c1hi + hi2f(p2);
            if (STORE) {
                gated32[(size_t)(r0 + row) * 64 + word] =
                    (uint32_t)f2b(glo) | ((uint32_t)f2b(ghi) << 16);
            }
            slo += glo; qlo = fmaf(glo, glo, qlo);
            shi += ghi; qhi = fmaf(ghi, ghi, qhi);
        }
    }
    // lanes {lr, lr+16, lr+32, lr+48} hold the same channel -> butterfly reduce
    slo += __shfl_xor(slo, 16, 64); slo += __shfl_xor(slo, 32, 64);
    qlo += __shfl_xor(qlo, 16, 64); qlo += __shfl_xor(qlo, 32, 64);
    shi += __shfl_xor(shi, 16, 64); shi += __shfl_xor(shi, 32, 64);
    qhi += __shfl_xor(qhi, 16, 64); qhi += __shfl_xor(qhi, 32, 64);
    if (lane < 16) {
        atomicAdd(&stats[word], slo);
        atomicAdd(&stats[128 + word], qlo);
        atomicAdd(&stats[64 + word], shi);
        atomicAdd(&stats[128 + 64 + word], qhi);
    }
}

// ------- finalize BN: scale/shift from sums -------
__global__ void k_fin(float* __restrict__ stats, const float* __restrict__ gg,
                      const float* __restrict__ bb, int nch, float invcnt,
                      int sumoff, int sqoff, int scoff, int shoff) {
    int c = threadIdx.x;
    if (c < nch) {
        float mean = stats[sumoff + c] * invcnt;
        float var  = fmaxf(stats[sqoff + c] * invcnt - mean * mean, 0.f);
        float sc   = gg[c] * rsqrtf(var + BN_EPS);
        stats[scoff + c] = sc;
        stats[shoff + c] = bb[c] - mean * sc;
    }
}

// ------- pass 2 (Path A): stream packed gated words -------
__global__ __launch_bounds__(256) void k_acts(
    const uint32_t* __restrict__ gated32, float* __restrict__ stats,
    u16* __restrict__ summed)
{
    __shared__ float red[4][64][2];
    int lane = threadIdx.x & 63;
    int w = threadIdx.x >> 6;
    float sa = stats[384 + lane],      ba = stats[512 + lane];
    float sb = stats[384 + 64 + lane], bb = stats[512 + 64 + lane];
    int wave = blockIdx.x * 4 + w, nw = gridDim.x * 4;
    float s2 = 0.f, q2 = 0.f;
    for (int n = wave; n < NN; n += nw) {
        const uint32_t* gr = gated32 + (size_t)n * MMN * 64;
        float s = 0.f;
#pragma unroll
        for (int m = 0; m < MMN; ++m) {
            uint32_t p = gr[m * 64 + lane];        // (filt[lane], core[lane])
            float f1 = b2f((u16)p) * sa + ba;
            float cc = hi2f(p) * sb + bb;
            s += sigm_f(f1) * sp_f(cc);
        }
        summed[(size_t)n * AFD + lane] = f2b(s);
        s2 += s; q2 += s * s;
    }
    red[w][lane][0] = s2; red[w][lane][1] = q2;
    __syncthreads();
    if (threadIdx.x < 64) {
        int c = threadIdx.x;
        float a = 0, b = 0;
#pragma unroll
        for (int ww = 0; ww < 4; ++ww) { a += red[ww][c][0]; b += red[ww][c][1]; }
        atomicAdd(&stats[256 + c], a);
        atomicAdd(&stats[320 + c], b);
    }
}

// dual 41-wide dot against LDS row (Path B fallback)
__device__ __forceinline__ void edge_dot(const float* fr, const float* wfa,
                                         const float* wfb, float& aa, float& ab) {
#pragma unroll
    for (int k4 = 0; k4 < 10; ++k4) {
        float4 f = *(const float4*)&fr[4 * k4];
        aa += f.x * wfa[4*k4] + f.y * wfa[4*k4+1] + f.z * wfa[4*k4+2] + f.w * wfa[4*k4+3];
        ab += f.x * wfb[4*k4] + f.y * wfb[4*k4+1] + f.z * wfb[4*k4+2] + f.w * wfb[4*k4+3];
    }
    aa += fr[40] * wfa[40];
    ab += fr[40] * wfb[40];
}

// ------- pass 2 (Path B fallback): recompute gated edge-sequentially -------
__global__ __launch_bounds__(256) void k_act(
    const uint32_t* __restrict__ C32, const float* __restrict__ nbrf,
    const int* __restrict__ nbridx, const float* __restrict__ convW,
    const float* __restrict__ convb, float* __restrict__ stats,
    u16* __restrict__ summed)
{
    __shared__ float fs[GROWS * 44];
    __shared__ float red[4][64][2];
    int lane = threadIdx.x & 63;
    int w = threadIdx.x >> 6;
    int r0 = blockIdx.x * GROWS;
    stage_nbrf(nbrf, r0, fs);
    float wfa[NBRF], wfb[NBRF];
#pragma unroll
    for (int k = 0; k < NBRF; ++k) {
        wfa[k] = convW[lane * KTOT + 128 + k];
        wfb[k] = convW[(lane + 64) * KTOT + 128 + k];
    }
    float biasa = convb[lane], biasb = convb[64 + lane];
    float sa = stats[384 + lane],      ba = stats[512 + lane];
    float sb = stats[384 + 64 + lane], bb = stats[512 + 64 + lane];
    __syncthreads();
    float s2 = 0.f, q2 = 0.f;
    float s = 0.f;
    float c1a = 0.f, c1b = 0.f;
    for (int rr = 0; rr < 24; ++rr) {
        int rl = w * 24 + rr;
        int r = r0 + rl;
        if ((rr % MMN) == 0) {
            int n = r / MMN;
            uint32_t p1 = C32[(size_t)n * 128 + lane];
            c1a = b2f((u16)p1); c1b = b2f((u16)(p1 >> 16));
            s = 0.f;
        }
        int j = nbridx[r];
        uint32_t p2 = C32[(size_t)j * 128 + 64 + lane];
        float aa = c1a + b2f((u16)p2) + biasa;
        float ab = c1b + b2f((u16)(p2 >> 16)) + biasb;
        edge_dot(&fs[rl * 44], wfa, wfb, aa, ab);
        float f1 = aa * sa + ba;
        float cc = ab * sb + bb;
        s += sigm_f(f1) * sp_f(cc);
        if ((rr % MMN) == MMN - 1) {
            int n = r / MMN;
            summed[(size_t)n * AFD + lane] = f2b(s);
            s2 += s; q2 += s * s;
        }
    }
    red[w][lane][0] = s2; red[w][lane][1] = q2;
    __syncthreads();
    if (threadIdx.x < 64) {
        int c = threadIdx.x;
        float a = 0, b = 0;
#pragma unroll
        for (int ww = 0; ww < 4; ++ww) { a += red[ww][c][0]; b += red[ww][c][1]; }
        atomicAdd(&stats[256 + c], a);
        atomicAdd(&stats[320 + c], b);
    }
}

// ------- h = softplus(h + BN2(summed))  (bf16 h) -------
__global__ void k_update(u16* __restrict__ h, const u16* __restrict__ summed,
                         const float* __restrict__ stats) {
    int i = blockIdx.x * blockDim.x + threadIdx.x;
    int st = gridDim.x * blockDim.x;
    int c = threadIdx.x & 63;
    float sc = stats[640 + c], shf = stats[704 + c];
    for (; i < NN * AFD; i += st) {
        float x = b2f(h[i]) + b2f(summed[i]) * sc + shf;
        h[i] = f2b(sp_f(x));
    }
}

// ------- row-normalize + mean-pool per crystal -------
__global__ __launch_bounds__(256) void k_pool(const u16* __restrict__ h,
                                              const int* __restrict__ cry,
                                              float* __restrict__ pooled) {
    __shared__ float red[4][64];
    int lane = threadIdx.x & 63, w = threadIdx.x >> 6;
    int b = blockIdx.x;
    float acc = 0.f;
    for (int a = w; a < NAA; a += 4) {
        int idx = cry[b * NAA + a];
        float v = b2f(h[(size_t)idx * AFD + lane]);
        float s2 = v * v;
#pragma unroll
        for (int o = 32; o > 0; o >>= 1) s2 += __shfl_xor(s2, o, 64);
        acc += v / fmaxf(sqrtf(s2), 1e-12f);
    }
    red[w][lane] = acc;
    __syncthreads();
    if (threadIdx.x < 64) {
        float s = red[0][threadIdx.x] + red[1][threadIdx.x] +
                  red[2][threadIdx.x] + red[3][threadIdx.x];
        pooled[b * AFD + threadIdx.x] = s * (1.f / NAA);
    }
}

// ------- MLP head (fp32 out) -------
__global__ __launch_bounds__(64) void k_head(const float* __restrict__ pooled,
    const float* __restrict__ fc1W, const float* __restrict__ fc1b,
    const float* __restrict__ fc2W, const float* __restrict__ fc2b,
    const float* __restrict__ outW, const float* __restrict__ outb,
    float* __restrict__ props) {
    __shared__ float W1[64 * 65], W2[64 * 65], zbuf[64], pbuf[64];
    int l = threadIdx.x;
    for (int e = l; e < 64 * 64; e += 64) {
        int o = e >> 6, k = e & 63;
        W1[o * 65 + k] = fc1W[e];
        W2[o * 65 + k] = fc2W[e];
    }
    int b = blockIdx.x;
    pbuf[l] = pooled[b * AFD + l];
    __syncthreads();
    float acc = fc1b[l];
#pragma unroll
    for (int k = 0; k < 64; ++k) acc += pbuf[k] * W1[l * 65 + k];
    zbuf[l] = sp_f(acc);
    __syncthreads();
    acc = fc2b[l];
#pragma unroll
    for (int k = 0; k < 64; ++k) acc += zbuf[k] * W2[l * 65 + k];
    float v = sp_f(acc) * outW[l];
#pragma unroll
    for (int o = 32; o > 0; o >>= 1) v += __shfl_xor(v, o, 64);
    if (l == 0) props[b] = v + outb[0];
}

extern "C" void kernel_launch(void* const* d_in, const int* in_sizes, int n_in,
                              void* d_out, int out_size, void* d_ws, size_t ws_size,
                              hipStream_t stream) {
    const float* atom  = (const float*)d_in[0];
    const float* nbrf  = (const float*)d_in[1];
    const int* nbridx  = (const int*)d_in[2];
    const int* cry     = (const int*)d_in[3];
    const float* mask  = (const float*)d_in[4];
    const float* embW  = (const float*)d_in[5];
    const float* convW = (const float*)d_in[6];
    const float* convb = (const float*)d_in[7];
    const float* bn1g  = (const float*)d_in[8];
    const float* bn1b  = (const float*)d_in[9];
    const float* bn2g  = (const float*)d_in[10];
    const float* bn2b  = (const float*)d_in[11];
    const float* fc1W  = (const float*)d_in[12];
    const float* fc1b  = (const float*)d_in[13];
    const float* fc2W  = (const float*)d_in[14];
    const float* fc2b  = (const float*)d_in[15];
    const float* outW  = (const float*)d_in[16];
    const float* outb  = (const float*)d_in[17];

    char* ws = (char*)d_ws;
    float* stats    = (float*)ws;                      // 768 floats
    float* pooled   = (float*)(ws + 4096);             // 128,000 B
    u16*   h        = (u16*)(ws + (1u << 20));         // 6.4 MB
    u16*   summed   = (u16*)(ws + (8u << 20));         // 6.4 MB
    uint32_t* C32   = (uint32_t*)(ws + (16u << 20));   // 25.6 MB
    uint32_t* gated32 = (uint32_t*)(ws + (48u << 20)); // 153.6 MB (Path A only)
    const bool bigws = ws_size >= (size_t)(48u << 20) + 153600000u;

    float* out_props = (float*)d_out;

    k_mask<<<2048, 256, 0, stream>>>(atom, mask, (float*)d_out);
    k_emb<<<512, 256, 0, stream>>>(atom, mask, embW, h);
    for (int i = 0; i < 3; ++i) {
        hipMemsetAsync(stats, 0, 384 * sizeof(float), stream);
        k_cn<<<1024, 256, 0, stream>>>(h, convW + (size_t)i * GCH * KTOT, C32);
        if (bigws)
            k_gs9<true><<<NMROWS / G48, 256, 0, stream>>>(C32, nbrf, nbridx,
                convW + (size_t)i * GCH * KTOT, convb + (size_t)i * GCH, stats, gated32);
        else
            k_gs9<false><<<NMROWS / G48, 256, 0, stream>>>(C32, nbrf, nbridx,
                convW + (size_t)i * GCH * KTOT, convb + (size_t)i * GCH, stats, gated32);
        k_fin<<<1, 128, 0, stream>>>(stats, bn1g + (size_t)i * GCH, bn1b + (size_t)i * GCH,
                                     128, 1.f / NMROWS, 0, 128, 384, 512);
        if (bigws)
            k_acts<<<2048, 256, 0, stream>>>(gated32, stats, summed);
        else
            k_act<<<NMROWS / GROWS, 256, 0, stream>>>(C32, nbrf, nbridx,
                convW + (size_t)i * GCH * KTOT, convb + (size_t)i * GCH, stats, summed);
        k_fin<<<1, 128, 0, stream>>>(stats, bn2g + (size_t)i * AFD, bn2b + (size_t)i * AFD,
                                     64, 1.f / NN, 256, 320, 640, 704);
        k_update<<<1024, 256, 0, stream>>>(h, summed, stats);
    }
    k_pool<<<BBC, 256, 0, stream>>>(h, cry, pooled);
    k_head<<<BBC, 64, 0, stream>>>(pooled, fc1W, fc1b, fc2W, fc2b, outW, outb, out_props);
}

// Round 7
// 1509.864 us; speedup vs baseline: 1.8259x; 1.0198x over previous
//
#include <hip/hip_runtime.h>
#include <hip/hip_bf16.h>
#include <stdint.h>

#define NN      50000
#define MMN     12
#define NMROWS  600000
#define ORIGF   92
#define NBRF    41
#define AFD     64
#define GCH     128
#define KTOT    169
#define BBC     500
#define NAA     100
#define BN_EPS  1e-5f
#define GROWS   96
#define G48     48

typedef unsigned short u16;
typedef __attribute__((ext_vector_type(8))) short bf16x8;
typedef __attribute__((ext_vector_type(4))) float f32x4;
typedef __attribute__((ext_vector_type(4))) unsigned int u32x4;

__device__ __forceinline__ float b2f(u16 u) {
    union { uint32_t i; float f; } v; v.i = ((uint32_t)u) << 16; return v.f;
}
__device__ __forceinline__ float hi2f(uint32_t p) {
    union { uint32_t i; float f; } v; v.i = p & 0xffff0000u; return v.f;
}
__device__ __forceinline__ u16 f2b(float f) {
    __hip_bfloat16 h = __float2bfloat16(f);
    return *(u16*)&h;
}
// branchless fast softplus: max(x,0) + log(1 + exp(-|x|))
__device__ __forceinline__ float sp_f(float x) {
    return fmaxf(x, 0.f) + __logf(1.f + __expf(-fabsf(x)));
}
__device__ __forceinline__ float sigm_f(float x) {
    return __builtin_amdgcn_rcpf(1.f + __expf(-x));
}

// ---------------- one-time: nbr_fea fp32 -> bf16 in As tile layout ----------------
// out[row*48 + k]: k<41 = bf16(nbrf), k=41 = 1.0 (bias col, layer-independent),
// k=42..47 = 0. Numerically identical to the old in-kernel conversion.
__global__ void k_prep(const float* __restrict__ nbrf, uint32_t* __restrict__ out) {
    int i = blockIdx.x * blockDim.x + threadIdx.x;
    int st = gridDim.x * blockDim.x;
    for (; i < NMROWS * 24; i += st) {      // one u32 = 2 cols
        int row = i / 24, k = (i - row * 24) * 2;
        const float* r = nbrf + (size_t)row * NBRF;
        uint32_t w0 = (k < 41) ? (uint32_t)f2b(r[k]) : 0u;
        uint32_t w1 = (k + 1 < 41) ? (uint32_t)f2b(r[k + 1])
                     : ((k + 1 == 41) ? 0x3F80u : 0u);
        out[i] = w0 | (w1 << 16);
    }
}

// ---------------- output 1: atom_fea * mask (fp32) ----------------
__global__ void k_mask(const float* __restrict__ atom, const float* __restrict__ mask,
                       float* __restrict__ dout) {
    int i = blockIdx.x * blockDim.x + threadIdx.x;
    int stride = gridDim.x * blockDim.x;
    for (; i < NN * ORIGF; i += stride) {
        int k = i % ORIGF;
        dout[BBC + i] = atom[i] * mask[k];
    }
}

// ---------------- h = (atom*mask) @ emb_W^T  (bf16 out) ----------------
__global__ __launch_bounds__(256, 2) void k_emb(const float* __restrict__ atom,
                                                const float* __restrict__ mask,
                                                const float* __restrict__ embW,
                                                u16* __restrict__ h) {
    __shared__ float xs[4 * 96];
    int lane = threadIdx.x & 63;
    int w = threadIdx.x >> 6;
    float wr[ORIGF];
#pragma unroll
    for (int k = 0; k < ORIGF; ++k) wr[k] = embW[lane * ORIGF + k];
    float m1 = mask[lane];
    float m2 = (lane < ORIGF - 64) ? mask[64 + lane] : 0.f;
    for (int base = blockIdx.x * 4; base < NN; base += gridDim.x * 4) {
        int n = base + w;   // NN % 4 == 0
        xs[w * 96 + lane] = atom[(size_t)n * ORIGF + lane] * m1;
        if (lane < ORIGF - 64)
            xs[w * 96 + 64 + lane] = atom[(size_t)n * ORIGF + 64 + lane] * m2;
        __syncthreads();
        float acc = 0.f;
#pragma unroll
        for (int k4 = 0; k4 < ORIGF / 4; ++k4) {
            float4 f = *(const float4*)&xs[w * 96 + 4 * k4];
            acc += f.x * wr[4*k4] + f.y * wr[4*k4+1] + f.z * wr[4*k4+2] + f.w * wr[4*k4+3];
        }
        h[(size_t)n * AFD + lane] = f2b(acc);
        __syncthreads();
    }
}

// ------- C (bf16 pairs): (h@Wc^T | h@Wn^T) -------
// u32 word layout: C32[n*128 + lane]      = (C1[ch=lane], C1[ch=lane+64])
//                  C32[n*128 + 64 + lane] = (C2[ch=lane], C2[ch=lane+64])
__global__ __launch_bounds__(256, 2) void k_cn(const u16* __restrict__ h,
                                               const float* __restrict__ convW,
                                               uint32_t* __restrict__ C32) {
    __shared__ float xs[2 * AFD];
    int lane = threadIdx.x & 63;
    int w = threadIdx.x >> 6;
    int half = w & 1;
    int sub = w >> 1;
    int koff = half * AFD;
    float wa[AFD], wb[AFD];
#pragma unroll
    for (int k = 0; k < AFD; ++k) {
        wa[k] = convW[lane * KTOT + koff + k];
        wb[k] = convW[(lane + 64) * KTOT + koff + k];
    }
    for (int base = blockIdx.x * 2; base < NN; base += gridDim.x * 2) {
        int n = base + sub;   // NN % 2 == 0
        if (half == 0) xs[sub * AFD + lane] = b2f(h[(size_t)n * AFD + lane]);
        __syncthreads();
        float aa = 0.f, ab = 0.f;
#pragma unroll
        for (int k4 = 0; k4 < AFD / 4; ++k4) {
            float4 f = *(const float4*)&xs[sub * AFD + 4 * k4];
            aa += f.x * wa[4*k4] + f.y * wa[4*k4+1] + f.z * wa[4*k4+2] + f.w * wa[4*k4+3];
            ab += f.x * wb[4*k4] + f.y * wb[4*k4+1] + f.z * wb[4*k4+2] + f.w * wb[4*k4+3];
        }
        C32[(size_t)n * 128 + half * 64 + lane] = (uint32_t)f2b(aa) | ((uint32_t)f2b(ab) << 16);
        __syncthreads();
    }
}

// stage 96 fp32 rows of nbr_fea into fs[row*44 + k]  (Path B fallback only)
__device__ __forceinline__ void stage_nbrf(const float* nbrf, int r0, float* fs) {
    const float4* src = (const float4*)(nbrf + (size_t)r0 * NBRF);
    for (int t = threadIdx.x; t < (GROWS * NBRF) / 4; t += 256) {
        float4 f = src[t];
        float vals[4] = {f.x, f.y, f.z, f.w};
#pragma unroll
        for (int j = 0; j < 4; ++j) {
            int e = t * 4 + j;
            int row = e / NBRF;
            int k = e - row * NBRF;
            fs[row * 44 + k] = vals[j];
        }
    }
}

// ------- pass 1 (MFMA): gated = nbrf @ Wf^T (+bias) + C1 + C2 -------
// 48 edges x 128 ch per block, __launch_bounds__(256,6): LDS 18.75KB allows 8
// blocks/CU, VGPR cap 85 keeps per-wave load batching deep (R6 lesson: (256,8)
// forced VGPR=32 and tanked delivered BW to 0.9 TB/s).
// PREP: As staged by raw u32x4 copy from pre-converted bf16 nbrf (k_prep);
// !PREP: fp32 load + convert (fallback when workspace too small for nbrf16).
// D layout (HW-verified): col = lane&15, row = (lane>>4)*4 + reg. A/B share the
// identical lane->k mapping so HW K-permutation cancels; k=41 col carries bias.
template<bool STORE, bool PREP>
__global__ __launch_bounds__(256, 6) void k_gs10(
    const uint32_t* __restrict__ C32, const float* __restrict__ nbrf,
    const u16* __restrict__ nbrf16, const int* __restrict__ nbridx,
    const float* __restrict__ convW, const float* __restrict__ convb,
    float* __restrict__ stats, uint32_t* __restrict__ gated32)
{
    __shared__ __align__(16) u16 As[G48 * 48];     // 4608 B, k=0..47 (41=bias)
    __shared__ uint32_t C2s[G48 * 68];             // 13056 B, stride 68
    __shared__ uint32_t C1s[4 * 68];               // 1088 B
    const int tid  = threadIdx.x;
    const int lane = tid & 63;
    const int w    = tid >> 6;
    const int lr   = lane & 15;
    const int lg   = lane >> 4;
    const int r0    = blockIdx.x * G48;
    const int nbase = blockIdx.x * 4;              // 4 atoms per block
    const int rowb  = w * 12;                      // rows staged by this wave

    // ---- issue C1 (4 atoms x 64 words, 1 coalesced load/thread) ----
    uint32_t c1v = C32[(size_t)(nbase + w) * 128 + lane];
    // ---- issue C2: 12 rows/wave; nbridx via uniform s_loads ----
    const int* nb = nbridx + r0 + rowb;
    uint32_t c2v[12];
#pragma unroll
    for (int rr = 0; rr < 12; ++rr) {
        int j = nb[rr];
        c2v[rr] = C32[(size_t)j * 128 + 64 + lane];
    }
    // ---- As staging ----
    if (PREP) {
        // raw copy: 48 rows x 48 u16 = 4608 B = 288 u32x4 (bias col prebaked)
        const u32x4* s4 = (const u32x4*)(nbrf16 + (size_t)r0 * 48);
        u32x4* d4 = (u32x4*)As;
        d4[tid] = s4[tid];
        if (tid < 32) d4[256 + tid] = s4[256 + tid];
    } else {
        const float4* src4 = (const float4*)(nbrf + (size_t)r0 * NBRF);
        float4 af[2];
#pragma unroll
        for (int it = 0; it < 2; ++it) {
            int t = tid + it * 256;
            if (it == 0 || t < 492) af[it] = src4[t];    // 492 = 48*41/4
        }
#pragma unroll
        for (int it = 0; it < 2; ++it) {
            int t = tid + it * 256;
            if (it == 0 || t < 492) {
                float4 f = af[it];
                float vals[4] = {f.x, f.y, f.z, f.w};
#pragma unroll
                for (int jj = 0; jj < 4; ++jj) {
                    int e = t * 4 + jj;
                    int row = e / NBRF;
                    int k = e - row * NBRF;
                    As[row * 48 + k] = f2b(vals[jj]);
                }
            }
        }
        for (int e = tid; e < 336; e += 256) {       // 48*7 pad elems
            int row = e / 7;
            int k = 41 + (e - row * 7);
            As[row * 48 + k] = (k == 41) ? (u16)0x3F80 : (u16)0;
        }
    }
    // ---- B frags direct from global (L2-hot), same k-mapping as A ----
    const int chlo = w * 16 + lr;
    const int chhi = chlo + 64;
    const float* wlo = convW + (size_t)chlo * KTOT + 128;
    const float* whi = convW + (size_t)chhi * KTOT + 128;
    bf16x8 bl0, bh0;
    bf16x8 bl1 = {0,0,0,0,0,0,0,0}, bh1 = {0,0,0,0,0,0,0,0};
#pragma unroll
    for (int e = 0; e < 8; ++e) {
        bl0[e] = (short)f2b(wlo[8 * lg + e]);
        bh0[e] = (short)f2b(whi[8 * lg + e]);
    }
    if (lg == 0) {
#pragma unroll
        for (int e = 0; e < 8; ++e) {
            bl1[e] = (short)f2b(wlo[32 + e]);
            bh1[e] = (short)f2b(whi[32 + e]);
        }
    } else if (lg == 1) {
        bl1[0] = (short)f2b(wlo[40]); bl1[1] = (short)f2b(convb[chlo]);
        bh1[0] = (short)f2b(whi[40]); bh1[1] = (short)f2b(convb[chhi]);
    }
    // ---- C1/C2 LDS writes ----
    C1s[w * 68 + lane] = c1v;
#pragma unroll
    for (int rr = 0; rr < 12; ++rr) C2s[(rowb + rr) * 68 + lane] = c2v[rr];
    __syncthreads();

    // ---- MFMA: 3 M-tiles x 2 channel halves ----
    f32x4 acc[3][2];
    const f32x4 z = {0.f, 0.f, 0.f, 0.f};
    const bf16x8 zb = {0,0,0,0,0,0,0,0};
#pragma unroll
    for (int mt = 0; mt < 3; ++mt) {
        const u16* ap = &As[(mt * 16 + lr) * 48 + 8 * lg];
        bf16x8 a0 = *(const bf16x8*)ap;
        bf16x8 a1 = zb;
        if (lg < 2) a1 = *(const bf16x8*)(ap + 32);   // k = 32+8lg..39+8lg (<48)
        acc[mt][0] = __builtin_amdgcn_mfma_f32_16x16x32_bf16(a1, bl1,
                     __builtin_amdgcn_mfma_f32_16x16x32_bf16(a0, bl0, z, 0, 0, 0), 0, 0, 0);
        acc[mt][1] = __builtin_amdgcn_mfma_f32_16x16x32_bf16(a1, bh1,
                     __builtin_amdgcn_mfma_f32_16x16x32_bf16(a0, bh0, z, 0, 0, 0), 0, 0, 0);
    }

    // ---- epilogue: combine with C1+C2 (LDS), pack-store gated, stats ----
    const int word = w * 16 + lr;   // u32 word = (ch, ch+64)
    float slo = 0.f, qlo = 0.f, shi = 0.f, qhi = 0.f;
#pragma unroll
    for (int mt = 0; mt < 3; ++mt) {
        int atomi = (mt * 16 + 4 * lg) / 12;   // 4-row groups never cross atoms
        uint32_t p1 = C1s[atomi * 68 + word];
        float c1lo = b2f((u16)p1), c1hi = hi2f(p1);
#pragma unroll
        for (int rg = 0; rg < 4; ++rg) {
            int row = mt * 16 + 4 * lg + rg;
            uint32_t p2 = C2s[row * 68 + word];
            float glo = acc[mt][0][rg] + c1lo + b2f((u16)p2);
            float ghi = acc[mt][1][rg] + c1hi + hi2f(p2);
            if (STORE) {
                gated32[(size_t)(r0 + row) * 64 + word] =
                    (uint32_t)f2b(glo) | ((uint32_t)f2b(ghi) << 16);
            }
            slo += glo; qlo = fmaf(glo, glo, qlo);
            shi += ghi; qhi = fmaf(ghi, ghi, qhi);
        }
    }
    // lanes {lr, lr+16, lr+32, lr+48} hold the same channel -> butterfly reduce
    slo += __shfl_xor(slo, 16, 64); slo += __shfl_xor(slo, 32, 64);
    qlo += __shfl_xor(qlo, 16, 64); qlo += __shfl_xor(qlo, 32, 64);
    shi += __shfl_xor(shi, 16, 64); shi += __shfl_xor(shi, 32, 64);
    qhi += __shfl_xor(qhi, 16, 64); qhi += __shfl_xor(qhi, 32, 64);
    if (lane < 16) {
        atomicAdd(&stats[word], slo);
        atomicAdd(&stats[128 + word], qlo);
        atomicAdd(&stats[64 + word], shi);
        atomicAdd(&stats[128 + 64 + word], qhi);
    }
}

// ------- pass 2 (Path A): stream packed gated words; BN1 finalized inline -------
__global__ __launch_bounds__(256) void k_acts(
    const uint32_t* __restrict__ gated32, const float* __restrict__ stats,
    const float* __restrict__ g1, const float* __restrict__ b1,
    float* __restrict__ ostats, u16* __restrict__ summed)
{
    __shared__ float red[4][64][2];
    int lane = threadIdx.x & 63;
    int w = threadIdx.x >> 6;
    const float invn = 1.f / (float)NMROWS;
    float m1 = stats[lane] * invn;
    float v1 = fmaxf(stats[128 + lane] * invn - m1 * m1, 0.f);
    float sa = g1[lane] * rsqrtf(v1 + BN_EPS);
    float ba = b1[lane] - m1 * sa;
    float m2 = stats[64 + lane] * invn;
    float v2 = fmaxf(stats[192 + lane] * invn - m2 * m2, 0.f);
    float sb = g1[64 + lane] * rsqrtf(v2 + BN_EPS);
    float bb = b1[64 + lane] - m2 * sb;
    int wave = blockIdx.x * 4 + w, nw = gridDim.x * 4;
    float s2 = 0.f, q2 = 0.f;
    for (int n = wave; n < NN; n += nw) {
        const uint32_t* gr = gated32 + (size_t)n * MMN * 64;
        float s = 0.f;
#pragma unroll
        for (int m = 0; m < MMN; ++m) {
            uint32_t p = gr[m * 64 + lane];        // (filt[lane], core[lane])
            float f1 = b2f((u16)p) * sa + ba;
            float cc = hi2f(p) * sb + bb;
            s += sigm_f(f1) * sp_f(cc);
        }
        summed[(size_t)n * AFD + lane] = f2b(s);
        s2 += s; q2 += s * s;
    }
    red[w][lane][0] = s2; red[w][lane][1] = q2;
    __syncthreads();
    if (threadIdx.x < 64) {
        int c = threadIdx.x;
        float a = 0, b = 0;
#pragma unroll
        for (int ww = 0; ww < 4; ++ww) { a += red[ww][c][0]; b += red[ww][c][1]; }
        atomicAdd(&ostats[256 + c], a);
        atomicAdd(&ostats[320 + c], b);
    }
}

// dual 41-wide dot against LDS row (Path B fallback)
__device__ __forceinline__ void edge_dot(const float* fr, const float* wfa,
                                         const float* wfb, float& aa, float& ab) {
#pragma unroll
    for (int k4 = 0; k4 < 10; ++k4) {
        float4 f = *(const float4*)&fr[4 * k4];
        aa += f.x * wfa[4*k4] + f.y * wfa[4*k4+1] + f.z * wfa[4*k4+2] + f.w * wfa[4*k4+3];
        ab += f.x * wfb[4*k4] + f.y * wfb[4*k4+1] + f.z * wfb[4*k4+2] + f.w * wfb[4*k4+3];
    }
    aa += fr[40] * wfa[40];
    ab += fr[40] * wfb[40];
}

// ------- pass 2 (Path B fallback): recompute gated edge-sequentially -------
__global__ __launch_bounds__(256) void k_act(
    const uint32_t* __restrict__ C32, const float* __restrict__ nbrf,
    const int* __restrict__ nbridx, const float* __restrict__ convW,
    const float* __restrict__ convb, const float* __restrict__ g1,
    const float* __restrict__ b1, float* __restrict__ stats,
    u16* __restrict__ summed)
{
    __shared__ float fs[GROWS * 44];
    __shared__ float red[4][64][2];
    int lane = threadIdx.x & 63;
    int w = threadIdx.x >> 6;
    int r0 = blockIdx.x * GROWS;
    stage_nbrf(nbrf, r0, fs);
    float wfa[NBRF], wfb[NBRF];
#pragma unroll
    for (int k = 0; k < NBRF; ++k) {
        wfa[k] = convW[lane * KTOT + 128 + k];
        wfb[k] = convW[(lane + 64) * KTOT + 128 + k];
    }
    float biasa = convb[lane], biasb = convb[64 + lane];
    const float invn = 1.f / (float)NMROWS;
    float m1 = stats[lane] * invn;
    float v1 = fmaxf(stats[128 + lane] * invn - m1 * m1, 0.f);
    float sa = g1[lane] * rsqrtf(v1 + BN_EPS);
    float ba = b1[lane] - m1 * sa;
    float m2 = stats[64 + lane] * invn;
    float v2 = fmaxf(stats[192 + lane] * invn - m2 * m2, 0.f);
    float sb = g1[64 + lane] * rsqrtf(v2 + BN_EPS);
    float bb = b1[64 + lane] - m2 * sb;
    __syncthreads();
    float s2 = 0.f, q2 = 0.f;
    float s = 0.f;
    float c1a = 0.f, c1b = 0.f;
    for (int rr = 0; rr < 24; ++rr) {
        int rl = w * 24 + rr;
        int r = r0 + rl;
        if ((rr % MMN) == 0) {
            int n = r / MMN;
            uint32_t p1 = C32[(size_t)n * 128 + lane];
            c1a = b2f((u16)p1); c1b = b2f((u16)(p1 >> 16));
            s = 0.f;
        }
        int j = nbridx[r];
        uint32_t p2 = C32[(size_t)j * 128 + 64 + lane];
        float aa = c1a + b2f((u16)p2) + biasa;
        float ab = c1b + b2f((u16)(p2 >> 16)) + biasb;
        edge_dot(&fs[rl * 44], wfa, wfb, aa, ab);
        float f1 = aa * sa + ba;
        float cc = ab * sb + bb;
        s += sigm_f(f1) * sp_f(cc);
        if ((rr % MMN) == MMN - 1) {
            int n = r / MMN;
            summed[(size_t)n * AFD + lane] = f2b(s);
            s2 += s; q2 += s * s;
        }
    }
    red[w][lane][0] = s2; red[w][lane][1] = q2;
    __syncthreads();
    if (threadIdx.x < 64) {
        int c = threadIdx.x;
        float a = 0, b = 0;
#pragma unroll
        for (int ww = 0; ww < 4; ++ww) { a += red[ww][c][0]; b += red[ww][c][1]; }
        atomicAdd(&stats[256 + c], a);
        atomicAdd(&stats[320 + c], b);
    }
}

// ------- h = softplus(h + BN2(summed)); BN2 finalized inline -------
__global__ void k_update(u16* __restrict__ h, const u16* __restrict__ summed,
                         const float* __restrict__ stats,
                         const float* __restrict__ g2, const float* __restrict__ b2) {
    int i = blockIdx.x * blockDim.x + threadIdx.x;
    int st = gridDim.x * blockDim.x;
    int c = threadIdx.x & 63;
    const float invn = 1.f / (float)NN;
    float m = stats[256 + c] * invn;
    float var = fmaxf(stats[320 + c] * invn - m * m, 0.f);
    float sc = g2[c] * rsqrtf(var + BN_EPS);
    float shf = b2[c] - m * sc;
    for (; i < NN * AFD; i += st) {
        float x = b2f(h[i]) + b2f(summed[i]) * sc + shf;
        h[i] = f2b(sp_f(x));
    }
}

// ------- row-normalize + mean-pool per crystal -------
__global__ __launch_bounds__(256) void k_pool(const u16* __restrict__ h,
                                              const int* __restrict__ cry,
                                              float* __restrict__ pooled) {
    __shared__ float red[4][64];
    int lane = threadIdx.x & 63, w = threadIdx.x >> 6;
    int b = blockIdx.x;
    float acc = 0.f;
    for (int a = w; a < NAA; a += 4) {
        int idx = cry[b * NAA + a];
        float v = b2f(h[(size_t)idx * AFD + lane]);
        float s2 = v * v;
#pragma unroll
        for (int o = 32; o > 0; o >>= 1) s2 += __shfl_xor(s2, o, 64);
        acc += v / fmaxf(sqrtf(s2), 1e-12f);
    }
    red[w][lane] = acc;
    __syncthreads();
    if (threadIdx.x < 64) {
        float s = red[0][threadIdx.x] + red[1][threadIdx.x] +
                  red[2][threadIdx.x] + red[3][threadIdx.x];
        pooled[b * AFD + threadIdx.x] = s * (1.f / NAA);
    }
}

// ------- MLP head (fp32 out) -------
__global__ __launch_bounds__(64) void k_head(const float* __restrict__ pooled,
    const float* __restrict__ fc1W, const float* __restrict__ fc1b,
    const float* __restrict__ fc2W, const float* __restrict__ fc2b,
    const float* __restrict__ outW, const float* __restrict__ outb,
    float* __restrict__ props) {
    __shared__ float W1[64 * 65], W2[64 * 65], zbuf[64], pbuf[64];
    int l = threadIdx.x;
    for (int e = l; e < 64 * 64; e += 64) {
        int o = e >> 6, k = e & 63;
        W1[o * 65 + k] = fc1W[e];
        W2[o * 65 + k] = fc2W[e];
    }
    int b = blockIdx.x;
    pbuf[l] = pooled[b * AFD + l];
    __syncthreads();
    float acc = fc1b[l];
#pragma unroll
    for (int k = 0; k < 64; ++k) acc += pbuf[k] * W1[l * 65 + k];
    zbuf[l] = sp_f(acc);
    __syncthreads();
    acc = fc2b[l];
#pragma unroll
    for (int k = 0; k < 64; ++k) acc += zbuf[k] * W2[l * 65 + k];
    float v = sp_f(acc) * outW[l];
#pragma unroll
    for (int o = 32; o > 0; o >>= 1) v += __shfl_xor(v, o, 64);
    if (l == 0) props[b] = v + outb[0];
}

extern "C" void kernel_launch(void* const* d_in, const int* in_sizes, int n_in,
                              void* d_out, int out_size, void* d_ws, size_t ws_size,
                              hipStream_t stream) {
    const float* atom  = (const float*)d_in[0];
    const float* nbrf  = (const float*)d_in[1];
    const int* nbridx  = (const int*)d_in[2];
    const int* cry     = (const int*)d_in[3];
    const float* mask  = (const float*)d_in[4];
    const float* embW  = (const float*)d_in[5];
    const float* convW = (const float*)d_in[6];
    const float* convb = (const float*)d_in[7];
    const float* bn1g  = (const float*)d_in[8];
    const float* bn1b  = (const float*)d_in[9];
    const float* bn2g  = (const float*)d_in[10];
    const float* bn2b  = (const float*)d_in[11];
    const float* fc1W  = (const float*)d_in[12];
    const float* fc1b  = (const float*)d_in[13];
    const float* fc2W  = (const float*)d_in[14];
    const float* fc2b  = (const float*)d_in[15];
    const float* outW  = (const float*)d_in[16];
    const float* outb  = (const float*)d_in[17];

    char* ws = (char*)d_ws;
    float* stats    = (float*)ws;                      // 768 floats
    float* pooled   = (float*)(ws + 4096);             // 128,000 B
    u16*   h        = (u16*)(ws + (1u << 20));         // 6.4 MB
    u16*   summed   = (u16*)(ws + (8u << 20));         // 6.4 MB
    uint32_t* C32   = (uint32_t*)(ws + (16u << 20));   // 25.6 MB
    uint32_t* gated32 = (uint32_t*)(ws + (48u << 20)); // 153.6 MB
    u16* nbrf16 = (u16*)(ws + (size_t)(48u << 20) + 153600000u);   // 57.6 MB
    const size_t need1 = (size_t)(48u << 20) + 153600000u;
    const size_t need2 = need1 + 57600000u;
    const bool bigws = ws_size >= need1;
    const bool prep  = ws_size >= need2;

    float* out_props = (float*)d_out;

    if (prep) k_prep<<<2048, 256, 0, stream>>>(nbrf, (uint32_t*)nbrf16);
    k_mask<<<2048, 256, 0, stream>>>(atom, mask, (float*)d_out);
    k_emb<<<512, 256, 0, stream>>>(atom, mask, embW, h);
    for (int i = 0; i < 3; ++i) {
        hipMemsetAsync(stats, 0, 384 * sizeof(float), stream);
        k_cn<<<1024, 256, 0, stream>>>(h, convW + (size_t)i * GCH * KTOT, C32);
        if (bigws) {
            if (prep)
                k_gs10<true, true><<<NMROWS / G48, 256, 0, stream>>>(C32, nbrf, nbrf16,
                    nbridx, convW + (size_t)i * GCH * KTOT, convb + (size_t)i * GCH,
                    stats, gated32);
            else
                k_gs10<true, false><<<NMROWS / G48, 256, 0, stream>>>(C32, nbrf, nbrf16,
                    nbridx, convW + (size_t)i * GCH * KTOT, convb + (size_t)i * GCH,
                    stats, gated32);
            k_acts<<<1024, 256, 0, stream>>>(gated32, stats,
                bn1g + (size_t)i * GCH, bn1b + (size_t)i * GCH, stats, summed);
        } else {
            k_gs10<false, false><<<NMROWS / G48, 256, 0, stream>>>(C32, nbrf, nbrf16,
                nbridx, convW + (size_t)i * GCH * KTOT, convb + (size_t)i * GCH,
                stats, gated32);
            k_act<<<NMROWS / GROWS, 256, 0, stream>>>(C32, nbrf, nbridx,
                convW + (size_t)i * GCH * KTOT, convb + (size_t)i * GCH,
                bn1g + (size_t)i * GCH, bn1b + (size_t)i * GCH, stats, summed);
        }
        k_update<<<1024, 256, 0, stream>>>(h, summed, stats,
            bn2g + (size_t)i * AFD, bn2b + (size_t)i * AFD);
    }
    k_pool<<<BBC, 256, 0, stream>>>(h, cry, pooled);
    k_head<<<BBC, 64, 0, stream>>>(pooled, fc1W, fc1b, fc2W, fc2b, outW, outb, out_props);
}

// Round 8
// 963.147 us; speedup vs baseline: 2.8624x; 1.5676x over previous
//
#include <hip/hip_runtime.h>
#include <hip/hip_bf16.h>
#include <stdint.h>

#define NN      50000
#define MMN     12
#define NMROWS  600000
#define ORIGF   92
#define NBRF    41
#define AFD     64
#define GCH     128
#define KTOT    169
#define BBC     500
#define NAA     100
#define BN_EPS  1e-5f
#define GROWS   96

typedef unsigned short u16;
typedef __attribute__((ext_vector_type(8))) short bf16x8;
typedef __attribute__((ext_vector_type(4))) float f32x4;

__device__ __forceinline__ float b2f(u16 u) {
    union { uint32_t i; float f; } v; v.i = ((uint32_t)u) << 16; return v.f;
}
__device__ __forceinline__ float hi2f(uint32_t p) {
    union { uint32_t i; float f; } v; v.i = p & 0xffff0000u; return v.f;
}
__device__ __forceinline__ u16 f2b(float f) {
    __hip_bfloat16 h = __float2bfloat16(f);
    return *(u16*)&h;
}
// branchless fast softplus: max(x,0) + log(1 + exp(-|x|))
__device__ __forceinline__ float sp_f(float x) {
    return fmaxf(x, 0.f) + __logf(1.f + __expf(-fabsf(x)));
}
__device__ __forceinline__ float sigm_f(float x) {
    return __builtin_amdgcn_rcpf(1.f + __expf(-x));
}

// ------- fused: dout = atom*mask (fp32) AND h = (atom*mask) @ emb_W^T (bf16) -------
__global__ __launch_bounds__(256, 2) void k_embm(const float* __restrict__ atom,
                                                 const float* __restrict__ mask,
                                                 const float* __restrict__ embW,
                                                 u16* __restrict__ h,
                                                 float* __restrict__ dout) {
    __shared__ float xs[4 * 96];
    int lane = threadIdx.x & 63;
    int w = threadIdx.x >> 6;
    float wr[ORIGF];
#pragma unroll
    for (int k = 0; k < ORIGF; ++k) wr[k] = embW[lane * ORIGF + k];
    float m1 = mask[lane];
    float m2 = (lane < ORIGF - 64) ? mask[64 + lane] : 0.f;
    for (int base = blockIdx.x * 4; base < NN; base += gridDim.x * 4) {
        int n = base + w;   // NN % 4 == 0
        float v1 = atom[(size_t)n * ORIGF + lane] * m1;
        xs[w * 96 + lane] = v1;
        dout[BBC + (size_t)n * ORIGF + lane] = v1;
        if (lane < ORIGF - 64) {
            float v2 = atom[(size_t)n * ORIGF + 64 + lane] * m2;
            xs[w * 96 + 64 + lane] = v2;
            dout[BBC + (size_t)n * ORIGF + 64 + lane] = v2;
        }
        __syncthreads();
        float acc = 0.f;
#pragma unroll
        for (int k4 = 0; k4 < ORIGF / 4; ++k4) {
            float4 f = *(const float4*)&xs[w * 96 + 4 * k4];
            acc += f.x * wr[4*k4] + f.y * wr[4*k4+1] + f.z * wr[4*k4+2] + f.w * wr[4*k4+3];
        }
        h[(size_t)n * AFD + lane] = f2b(acc);
        __syncthreads();
    }
}

// ------- C32 via MFMA: replaces k_cn (which held 128 fp32 weights/thread) -------
// Block: 96 atom rows x 256 outputs (ch 0..127 x slice q in {Wc,Wn}).
// Wave w owns ch {w*16+lr, +64}; acc[mt][v], v = q*2 + (hi?1:0).
// Hs stride 72 u16 = 144 B: 16B-aligned b128 reads, 2-way banks (free).
// Same A/B lane->k mapping and D layout as the proven k_gs kernels.
__global__ __launch_bounds__(256, 2) void k_cnm(const u16* __restrict__ h,
                                                const float* __restrict__ convW,
                                                uint32_t* __restrict__ C32) {
    __shared__ __align__(16) u16 Hs[96 * 72];   // 13824 B
    const int tid  = threadIdx.x;
    const int lane = tid & 63;
    const int w    = tid >> 6;
    const int lr   = lane & 15;
    const int lg   = lane >> 4;
    const int r0   = blockIdx.x * 96;
    const int rows = (NN - r0 < 96) ? (NN - r0) : 96;   // tail block = 80 (5 MTs)

    // stage h rows (u32 granularity, coalesced): 96*32 u32, 12/thread
#pragma unroll
    for (int it = 0; it < 12; ++it) {
        int idx = tid + it * 256;
        int row = idx >> 5, col = idx & 31;
        if (row < rows)
            *(uint32_t*)&Hs[row * 72 + col * 2] =
                ((const uint32_t*)h)[(size_t)(r0 + row) * 32 + col];
    }
    // B frags: 4 channel-vectors of K=64 from L2-hot convW
    const int chlo = w * 16 + lr;
    bf16x8 bfr[4][2];
#pragma unroll
    for (int v = 0; v < 4; ++v) {
        int ch = chlo + (v & 1) * 64;
        int q  = v >> 1;
        const float* bp = convW + (size_t)ch * KTOT + q * 64;
#pragma unroll
        for (int e = 0; e < 8; ++e) {
            bfr[v][0][e] = (short)f2b(bp[8 * lg + e]);
            bfr[v][1][e] = (short)f2b(bp[32 + 8 * lg + e]);
        }
    }
    __syncthreads();

    f32x4 acc[6][4];
    const f32x4 z = {0.f, 0.f, 0.f, 0.f};
#pragma unroll
    for (int mt = 0; mt < 6; ++mt) {
        if (mt * 16 < rows) {
            const u16* ap = &Hs[(mt * 16 + lr) * 72 + 8 * lg];
            bf16x8 a0 = *(const bf16x8*)ap;
            bf16x8 a1 = *(const bf16x8*)(ap + 32);
#pragma unroll
            for (int v = 0; v < 4; ++v)
                acc[mt][v] = __builtin_amdgcn_mfma_f32_16x16x32_bf16(a1, bfr[v][1],
                             __builtin_amdgcn_mfma_f32_16x16x32_bf16(a0, bfr[v][0], z, 0, 0, 0), 0, 0, 0);
        }
    }
    // epilogue: C32[n*128 + q*64 + ch_word] = (D[ch], D[ch+64]) packed bf16
#pragma unroll
    for (int mt = 0; mt < 6; ++mt) {
#pragma unroll
        for (int rg = 0; rg < 4; ++rg) {
            int row = mt * 16 + 4 * lg + rg;
            if (row < rows) {
                size_t n = r0 + row;
                C32[n * 128 + chlo] =
                    (uint32_t)f2b(acc[mt][0][rg]) | ((uint32_t)f2b(acc[mt][1][rg]) << 16);
                C32[n * 128 + 64 + chlo] =
                    (uint32_t)f2b(acc[mt][2][rg]) | ((uint32_t)f2b(acc[mt][3][rg]) << 16);
            }
        }
    }
}

// stage 96 fp32 rows of nbr_fea into fs[row*44 + k]  (Path B fallback only)
__device__ __forceinline__ void stage_nbrf(const float* nbrf, int r0, float* fs) {
    const float4* src = (const float4*)(nbrf + (size_t)r0 * NBRF);
    for (int t = threadIdx.x; t < (GROWS * NBRF) / 4; t += 256) {
        float4 f = src[t];
        float vals[4] = {f.x, f.y, f.z, f.w};
#pragma unroll
        for (int j = 0; j < 4; ++j) {
            int e = t * 4 + j;
            int row = e / NBRF;
            int k = e - row * NBRF;
            fs[row * 44 + k] = vals[j];
        }
    }
}

// ------- pass 1 (MFMA, prefetched): gated = nbrf @ Wf^T (+bias) + C1 + C2 -------
// EXACT revert to the round-3 champion (171.5 us measured): GROWS=96,
// __launch_bounds__(256,4), VGPR 52 — the config where the compiler builds
// deep per-wave load batches (delivered BW 1.66 TB/s; all other geometries
// measured worse: G48 -> VGPR 28-32 -> 0.87-0.94 TB/s).
template<bool STORE>
__global__ __launch_bounds__(256, 4) void k_gs4(
    const uint32_t* __restrict__ C32, const float* __restrict__ nbrf,
    const int* __restrict__ nbridx, const float* __restrict__ convW,
    const float* __restrict__ convb, float* __restrict__ stats,
    uint32_t* __restrict__ gated32)
{
    __shared__ __align__(16) u16 As[GROWS * 56];   // 10752 B, k=0..55 (41=bias col)
    __shared__ uint32_t C2s[GROWS * 65];           // 24960 B, stride 65 (2-way banks)
    __shared__ uint32_t C1s[8 * 65];               // 2080 B
    const int tid  = threadIdx.x;
    const int lane = tid & 63;
    const int w    = tid >> 6;
    const int lr   = lane & 15;
    const int lg   = lane >> 4;
    const int r0    = blockIdx.x * GROWS;
    const int nbase = blockIdx.x * (GROWS / MMN);   // 8 atoms per block
    const int rowb  = w * 24;                       // this wave stages rows rowb..rowb+23

    // ---- issue C2 batch 1 (12 coalesced 256B rows per wave) ----
    uint32_t c2v[12];
#pragma unroll
    for (int rr = 0; rr < 12; ++rr) {
        int j = nbridx[r0 + rowb + rr];
        c2v[rr] = C32[(size_t)j * 128 + 64 + lane];
    }
    // ---- issue C1 (8 atoms x 64 words, 2 coalesced loads/thread) ----
    uint32_t c1v[2];
#pragma unroll
    for (int q = 0; q < 2; ++q) {
        int e = tid + q * 256;
        c1v[q] = C32[(size_t)(nbase + (e >> 6)) * 128 + (e & 63)];
    }
    // ---- As staging: 96x41 nbrf -> bf16 (vectorized, coalesced) ----
    const float4* src4 = (const float4*)(nbrf + (size_t)r0 * NBRF);  // 16B aligned
#pragma unroll
    for (int it = 0; it < 4; ++it) {
        int t = tid + it * 256;
        if (it < 3 || t < 984) {          // 984 = 96*41/4
            float4 f = src4[t];
            float vals[4] = {f.x, f.y, f.z, f.w};
#pragma unroll
            for (int jj = 0; jj < 4; ++jj) {
                int e = t * 4 + jj;
                int row = e / NBRF;
                int k = e - row * NBRF;
                As[row * 56 + k] = f2b(vals[jj]);
            }
        }
    }
    // ---- write C2 batch 1, issue batch 2 ----
#pragma unroll
    for (int rr = 0; rr < 12; ++rr) C2s[(rowb + rr) * 65 + lane] = c2v[rr];
#pragma unroll
    for (int rr = 0; rr < 12; ++rr) {
        int j = nbridx[r0 + rowb + 12 + rr];
        c2v[rr] = C32[(size_t)j * 128 + 64 + lane];
    }
#pragma unroll
    for (int q = 0; q < 2; ++q) {
        int e = tid + q * 256;
        C1s[(e >> 6) * 65 + (e & 63)] = c1v[q];
    }
    // ---- As pad: k=41 -> 1.0 (bias column), 42..55 -> 0 ----
#pragma unroll
    for (int it = 0; it < 6; ++it) {
        int e = tid + it * 256;
        if (it < 5 || e < 1440) {         // 1440 = 96*15
            int row = e / 15;
            int k = 41 + (e - row * 15);
            As[row * 56 + k] = (k == 41) ? (u16)0x3F80 : (u16)0;
        }
    }
    // ---- B frags direct from global (L2-hot), same k-mapping as A ----
    const int chlo = w * 16 + lr;
    const int chhi = chlo + 64;
    const float* wlo = convW + (size_t)chlo * KTOT + 128;
    const float* whi = convW + (size_t)chhi * KTOT + 128;
    bf16x8 bl0, bh0;
    bf16x8 bl1 = {0,0,0,0,0,0,0,0}, bh1 = {0,0,0,0,0,0,0,0};
#pragma unroll
    for (int e = 0; e < 8; ++e) {
        bl0[e] = (short)f2b(wlo[8 * lg + e]);
        bh0[e] = (short)f2b(whi[8 * lg + e]);
    }
    if (lg == 0) {
#pragma unroll
        for (int e = 0; e < 8; ++e) {
            bl1[e] = (short)f2b(wlo[32 + e]);
            bh1[e] = (short)f2b(whi[32 + e]);
        }
    } else if (lg == 1) {
        bl1[0] = (short)f2b(wlo[40]); bl1[1] = (short)f2b(convb[chlo]);
        bh1[0] = (short)f2b(whi[40]); bh1[1] = (short)f2b(convb[chhi]);
    }
    // ---- write C2 batch 2 ----
#pragma unroll
    for (int rr = 0; rr < 12; ++rr) C2s[(rowb + 12 + rr) * 65 + lane] = c2v[rr];
    __syncthreads();

    // ---- MFMA: 6 M-tiles x 2 channel halves ----
    f32x4 acc[6][2];
    const f32x4 z = {0.f, 0.f, 0.f, 0.f};
    const bf16x8 zb = {0,0,0,0,0,0,0,0};
#pragma unroll
    for (int mt = 0; mt < 6; ++mt) {
        const u16* ap = &As[(mt * 16 + lr) * 56 + 8 * lg];
        bf16x8 a0 = *(const bf16x8*)ap;
        bf16x8 a1 = zb;
        if (lg < 3) a1 = *(const bf16x8*)(ap + 32);   // k=32+8lg..39+8lg (<56)
        acc[mt][0] = __builtin_amdgcn_mfma_f32_16x16x32_bf16(a1, bl1,
                     __builtin_amdgcn_mfma_f32_16x16x32_bf16(a0, bl0, z, 0, 0, 0), 0, 0, 0);
        acc[mt][1] = __builtin_amdgcn_mfma_f32_16x16x32_bf16(a1, bh1,
                     __builtin_amdgcn_mfma_f32_16x16x32_bf16(a0, bh0, z, 0, 0, 0), 0, 0, 0);
    }

    // ---- epilogue: all operands in LDS; combine, store, stats ----
    const int word = w * 16 + lr;   // u32 word = (ch, ch+64)
    float slo = 0.f, qlo = 0.f, shi = 0.f, qhi = 0.f;
#pragma unroll
    for (int mt = 0; mt < 6; ++mt) {
#pragma unroll
        for (int rg = 0; rg < 4; ++rg) {
            int row = mt * 16 + 4 * lg + rg;
            uint32_t p1 = C1s[(row / MMN) * 65 + word];
            uint32_t p2 = C2s[row * 65 + word];
            float glo = acc[mt][0][rg] + b2f((u16)p1) + b2f((u16)p2);
            float ghi = acc[mt][1][rg] + hi2f(p1) + hi2f(p2);
            if (STORE) {
                gated32[(size_t)(r0 + row) * 64 + word] =
                    (uint32_t)f2b(glo) | ((uint32_t)f2b(ghi) << 16);
            }
            slo += glo; qlo = fmaf(glo, glo, qlo);
            shi += ghi; qhi = fmaf(ghi, ghi, qhi);
        }
    }
    // lanes {lr, lr+16, lr+32, lr+48} hold the same channel -> butterfly reduce
    slo += __shfl_xor(slo, 16, 64); slo += __shfl_xor(slo, 32, 64);
    qlo += __shfl_xor(qlo, 16, 64); qlo += __shfl_xor(qlo, 32, 64);
    shi += __shfl_xor(shi, 16, 64); shi += __shfl_xor(shi, 32, 64);
    qhi += __shfl_xor(qhi, 16, 64); qhi += __shfl_xor(qhi, 32, 64);
    if (lane < 16) {
        atomicAdd(&stats[word], slo);
        atomicAdd(&stats[128 + word], qlo);
        atomicAdd(&stats[64 + word], shi);
        atomicAdd(&stats[128 + 64 + word], qhi);
    }
}

// ------- pass 2 (Path A): stream packed gated words; BN1 finalized inline -------
__global__ __launch_bounds__(256) void k_acts(
    const uint32_t* __restrict__ gated32, const float* __restrict__ stats,
    const float* __restrict__ g1, const float* __restrict__ b1,
    float* __restrict__ ostats, u16* __restrict__ summed)
{
    __shared__ float red[4][64][2];
    int lane = threadIdx.x & 63;
    int w = threadIdx.x >> 6;
    const float invn = 1.f / (float)NMROWS;
    float m1 = stats[lane] * invn;
    float v1 = fmaxf(stats[128 + lane] * invn - m1 * m1, 0.f);
    float sa = g1[lane] * rsqrtf(v1 + BN_EPS);
    float ba = b1[lane] - m1 * sa;
    float m2 = stats[64 + lane] * invn;
    float v2 = fmaxf(stats[192 + lane] * invn - m2 * m2, 0.f);
    float sb = g1[64 + lane] * rsqrtf(v2 + BN_EPS);
    float bb = b1[64 + lane] - m2 * sb;
    int wave = blockIdx.x * 4 + w, nw = gridDim.x * 4;
    float s2 = 0.f, q2 = 0.f;
    for (int n = wave; n < NN; n += nw) {
        const uint32_t* gr = gated32 + (size_t)n * MMN * 64;
        float s = 0.f;
#pragma unroll
        for (int m = 0; m < MMN; ++m) {
            uint32_t p = gr[m * 64 + lane];        // (filt[lane], core[lane])
            float f1 = b2f((u16)p) * sa + ba;
            float cc = hi2f(p) * sb + bb;
            s += sigm_f(f1) * sp_f(cc);
        }
        summed[(size_t)n * AFD + lane] = f2b(s);
        s2 += s; q2 += s * s;
    }
    red[w][lane][0] = s2; red[w][lane][1] = q2;
    __syncthreads();
    if (threadIdx.x < 64) {
        int c = threadIdx.x;
        float a = 0, b = 0;
#pragma unroll
        for (int ww = 0; ww < 4; ++ww) { a += red[ww][c][0]; b += red[ww][c][1]; }
        atomicAdd(&ostats[256 + c], a);
        atomicAdd(&ostats[320 + c], b);
    }
}

// dual 41-wide dot against LDS row (Path B fallback)
__device__ __forceinline__ void edge_dot(const float* fr, const float* wfa,
                                         const float* wfb, float& aa, float& ab) {
#pragma unroll
    for (int k4 = 0; k4 < 10; ++k4) {
        float4 f = *(const float4*)&fr[4 * k4];
        aa += f.x * wfa[4*k4] + f.y * wfa[4*k4+1] + f.z * wfa[4*k4+2] + f.w * wfa[4*k4+3];
        ab += f.x * wfb[4*k4] + f.y * wfb[4*k4+1] + f.z * wfb[4*k4+2] + f.w * wfb[4*k4+3];
    }
    aa += fr[40] * wfa[40];
    ab += fr[40] * wfb[40];
}

// ------- pass 2 (Path B fallback): recompute gated edge-sequentially -------
__global__ __launch_bounds__(256) void k_act(
    const uint32_t* __restrict__ C32, const float* __restrict__ nbrf,
    const int* __restrict__ nbridx, const float* __restrict__ convW,
    const float* __restrict__ convb, const float* __restrict__ g1,
    const float* __restrict__ b1, float* __restrict__ stats,
    u16* __restrict__ summed)
{
    __shared__ float fs[GROWS * 44];
    __shared__ float red[4][64][2];
    int lane = threadIdx.x & 63;
    int w = threadIdx.x >> 6;
    int r0 = blockIdx.x * GROWS;
    stage_nbrf(nbrf, r0, fs);
    float wfa[NBRF], wfb[NBRF];
#pragma unroll
    for (int k = 0; k < NBRF; ++k) {
        wfa[k] = convW[lane * KTOT + 128 + k];
        wfb[k] = convW[(lane + 64) * KTOT + 128 + k];
    }
    float biasa = convb[lane], biasb = convb[64 + lane];
    const float invn = 1.f / (float)NMROWS;
    float m1 = stats[lane] * invn;
    float v1 = fmaxf(stats[128 + lane] * invn - m1 * m1, 0.f);
    float sa = g1[lane] * rsqrtf(v1 + BN_EPS);
    float ba = b1[lane] - m1 * sa;
    float m2 = stats[64 + lane] * invn;
    float v2 = fmaxf(stats[192 + lane] * invn - m2 * m2, 0.f);
    float sb = g1[64 + lane] * rsqrtf(v2 + BN_EPS);
    float bb = b1[64 + lane] - m2 * sb;
    __syncthreads();
    float s2 = 0.f, q2 = 0.f;
    float s = 0.f;
    float c1a = 0.f, c1b = 0.f;
    for (int rr = 0; rr < 24; ++rr) {
        int rl = w * 24 + rr;
        int r = r0 + rl;
        if ((rr % MMN) == 0) {
            int n = r / MMN;
            uint32_t p1 = C32[(size_t)n * 128 + lane];
            c1a = b2f((u16)p1); c1b = b2f((u16)(p1 >> 16));
            s = 0.f;
        }
        int j = nbridx[r];
        uint32_t p2 = C32[(size_t)j * 128 + 64 + lane];
        float aa = c1a + b2f((u16)p2) + biasa;
        float ab = c1b + b2f((u16)(p2 >> 16)) + biasb;
        edge_dot(&fs[rl * 44], wfa, wfb, aa, ab);
        float f1 = aa * sa + ba;
        float cc = ab * sb + bb;
        s += sigm_f(f1) * sp_f(cc);
        if ((rr % MMN) == MMN - 1) {
            int n = r / MMN;
            summed[(size_t)n * AFD + lane] = f2b(s);
            s2 += s; q2 += s * s;
        }
    }
    red[w][lane][0] = s2; red[w][lane][1] = q2;
    __syncthreads();
    if (threadIdx.x < 64) {
        int c = threadIdx.x;
        float a = 0, b = 0;
#pragma unroll
        for (int ww = 0; ww < 4; ++ww) { a += red[ww][c][0]; b += red[ww][c][1]; }
        atomicAdd(&stats[256 + c], a);
        atomicAdd(&stats[320 + c], b);
    }
}

// ------- h = softplus(h + BN2(summed)); BN2 finalized inline -------
__global__ void k_update(u16* __restrict__ h, const u16* __restrict__ summed,
                         const float* __restrict__ stats,
                         const float* __restrict__ g2, const float* __restrict__ b2) {
    int i = blockIdx.x * blockDim.x + threadIdx.x;
    int st = gridDim.x * blockDim.x;
    int c = threadIdx.x & 63;
    const float invn = 1.f / (float)NN;
    float m = stats[256 + c] * invn;
    float var = fmaxf(stats[320 + c] * invn - m * m, 0.f);
    float sc = g2[c] * rsqrtf(var + BN_EPS);
    float shf = b2[c] - m * sc;
    for (; i < NN * AFD; i += st) {
        float x = b2f(h[i]) + b2f(summed[i]) * sc + shf;
        h[i] = f2b(sp_f(x));
    }
}

// ------- row-normalize + mean-pool per crystal -------
__global__ __launch_bounds__(256) void k_pool(const u16* __restrict__ h,
                                              const int* __restrict__ cry,
                                              float* __restrict__ pooled) {
    __shared__ float red[4][64];
    int lane = threadIdx.x & 63, w = threadIdx.x >> 6;
    int b = blockIdx.x;
    float acc = 0.f;
    for (int a = w; a < NAA; a += 4) {
        int idx = cry[b * NAA + a];
        float v = b2f(h[(size_t)idx * AFD + lane]);
        float s2 = v * v;
#pragma unroll
        for (int o = 32; o > 0; o >>= 1) s2 += __shfl_xor(s2, o, 64);
        acc += v / fmaxf(sqrtf(s2), 1e-12f);
    }
    red[w][lane] = acc;
    __syncthreads();
    if (threadIdx.x < 64) {
        float s = red[0][threadIdx.x] + red[1][threadIdx.x] +
                  red[2][threadIdx.x] + red[3][threadIdx.x];
        pooled[b * AFD + threadIdx.x] = s * (1.f / NAA);
    }
}

// ------- MLP head (fp32 out) -------
__global__ __launch_bounds__(64) void k_head(const float* __restrict__ pooled,
    const float* __restrict__ fc1W, const float* __restrict__ fc1b,
    const float* __restrict__ fc2W, const float* __restrict__ fc2b,
    const float* __restrict__ outW, const float* __restrict__ outb,
    float* __restrict__ props) {
    __shared__ float W1[64 * 65], W2[64 * 65], zbuf[64], pbuf[64];
    int l = threadIdx.x;
    for (int e = l; e < 64 * 64; e += 64) {
        int o = e >> 6, k = e & 63;
        W1[o * 65 + k] = fc1W[e];
        W2[o * 65 + k] = fc2W[e];
    }
    int b = blockIdx.x;
    pbuf[l] = pooled[b * AFD + l];
    __syncthreads();
    float acc = fc1b[l];
#pragma unroll
    for (int k = 0; k < 64; ++k) acc += pbuf[k] * W1[l * 65 + k];
    zbuf[l] = sp_f(acc);
    __syncthreads();
    acc = fc2b[l];
#pragma unroll
    for (int k = 0; k < 64; ++k) acc += zbuf[k] * W2[l * 65 + k];
    float v = sp_f(acc) * outW[l];
#pragma unroll
    for (int o = 32; o > 0; o >>= 1) v += __shfl_xor(v, o, 64);
    if (l == 0) props[b] = v + outb[0];
}

extern "C" void kernel_launch(void* const* d_in, const int* in_sizes, int n_in,
                              void* d_out, int out_size, void* d_ws, size_t ws_size,
                              hipStream_t stream) {
    const float* atom  = (const float*)d_in[0];
    const float* nbrf  = (const float*)d_in[1];
    const int* nbridx  = (const int*)d_in[2];
    const int* cry     = (const int*)d_in[3];
    const float* mask  = (const float*)d_in[4];
    const float* embW  = (const float*)d_in[5];
    const float* convW = (const float*)d_in[6];
    const float* convb = (const float*)d_in[7];
    const float* bn1g  = (const float*)d_in[8];
    const float* bn1b  = (const float*)d_in[9];
    const float* bn2g  = (const float*)d_in[10];
    const float* bn2b  = (const float*)d_in[11];
    const float* fc1W  = (const float*)d_in[12];
    const float* fc1b  = (const float*)d_in[13];
    const float* fc2W  = (const float*)d_in[14];
    const float* fc2b  = (const float*)d_in[15];
    const float* outW  = (const float*)d_in[16];
    const float* outb  = (const float*)d_in[17];

    char* ws = (char*)d_ws;
    float* stats    = (float*)ws;                      // 768 floats
    float* pooled   = (float*)(ws + 4096);             // 128,000 B
    u16*   h        = (u16*)(ws + (1u << 20));         // 6.4 MB
    u16*   summed   = (u16*)(ws + (8u << 20));         // 6.4 MB
    uint32_t* C32   = (uint32_t*)(ws + (16u << 20));   // 25.6 MB
    uint32_t* gated32 = (uint32_t*)(ws + (48u << 20)); // 153.6 MB (Path A only)
    const bool bigws = ws_size >= (size_t)(48u << 20) + 153600000u;

    float* out_props = (float*)d_out;

    k_embm<<<512, 256, 0, stream>>>(atom, mask, embW, h, (float*)d_out);
    for (int i = 0; i < 3; ++i) {
        hipMemsetAsync(stats, 0, 384 * sizeof(float), stream);
        k_cnm<<<(NN + 95) / 96, 256, 0, stream>>>(h, convW + (size_t)i * GCH * KTOT, C32);
        if (bigws) {
            k_gs4<true><<<NMROWS / GROWS, 256, 0, stream>>>(C32, nbrf, nbridx,
                convW + (size_t)i * GCH * KTOT, convb + (size_t)i * GCH, stats, gated32);
            k_acts<<<2048, 256, 0, stream>>>(gated32, stats,
                bn1g + (size_t)i * GCH, bn1b + (size_t)i * GCH, stats, summed);
        } else {
            k_gs4<false><<<NMROWS / GROWS, 256, 0, stream>>>(C32, nbrf, nbridx,
                convW + (size_t)i * GCH * KTOT, convb + (size_t)i * GCH, stats, gated32);
            k_act<<<NMROWS / GROWS, 256, 0, stream>>>(C32, nbrf, nbridx,
                convW + (size_t)i * GCH * KTOT, convb + (size_t)i * GCH,
                bn1g + (size_t)i * GCH, bn1b + (size_t)i * GCH, stats, summed);
        }
        k_update<<<1024, 256, 0, stream>>>(h, summed, stats,
            bn2g + (size_t)i * AFD, bn2b + (size_t)i * AFD);
    }
    k_pool<<<BBC, 256, 0, stream>>>(h, cry, pooled);
    k_head<<<BBC, 64, 0, stream>>>(pooled, fc1W, fc1b, fc2W, fc2b, outW, outb, out_props);
}